// Round 9
// baseline (960.391 us; speedup 1.0000x reference)
//
#include <hip/hip_runtime.h>
#include <cstdint>
#include <cstddef>

// ---------------------------------------------------------------------------
// JAX threefry2x32 (20 rounds). fold_in(key(42), i) = threefry((0,42),(0,i))
// partitionable 32-bit random_bits: bits = o0 ^ o1 (XOR-fold)   [validated r2]
// uniform: u = bitcast((bits>>9)|0x3f800000) - 1.0f ; keep iff u < 0.9f
// ---------------------------------------------------------------------------
__host__ __device__ inline void tf2x32(uint32_t k0, uint32_t k1,
                                       uint32_t x0, uint32_t x1,
                                       uint32_t* o0, uint32_t* o1)
{
    uint32_t ks2 = k0 ^ k1 ^ 0x1BD11BDAu;
    x0 += k0; x1 += k1;
#define TF_R(r) do { x0 += x1; x1 = (x1 << (r)) | (x1 >> (32 - (r))); x1 ^= x0; } while (0)
    TF_R(13); TF_R(15); TF_R(26); TF_R(6);
    x0 += k1;  x1 += ks2 + 1u;
    TF_R(17); TF_R(29); TF_R(16); TF_R(24);
    x0 += ks2; x1 += k0 + 2u;
    TF_R(13); TF_R(15); TF_R(26); TF_R(6);
    x0 += k0;  x1 += k1 + 3u;
    TF_R(17); TF_R(29); TF_R(16); TF_R(24);
    x0 += k1;  x1 += ks2 + 4u;
    TF_R(13); TF_R(15); TF_R(26); TF_R(6);
    x0 += ks2; x1 += k0 + 5u;
#undef TF_R
    *o0 = x0; *o1 = x1;
}

__device__ inline float drop_scale(uint32_t fk0, uint32_t fk1, uint32_t idx)
{
    uint32_t o0, o1;
    tf2x32(fk0, fk1, 0u, idx, &o0, &o1);
    uint32_t bits = o0 ^ o1;
    float u = __uint_as_float((bits >> 9) | 0x3f800000u) - 1.0f;
    return (u < 0.9f) ? (1.0f / 0.9f) : 0.0f;
}

// bf16 helpers (round-to-nearest-even)
__device__ inline ushort bf16_rn(float f)
{
    uint32_t u = __float_as_uint(f);
    u += 0x7fffu + ((u >> 16) & 1u);
    return (ushort)(u >> 16);
}
__device__ inline float bf16_f(ushort h) { return __uint_as_float(((uint32_t)h) << 16); }
__device__ inline uint32_t pack2bf(float a, float b)
{
    return (uint32_t)bf16_rn(a) | ((uint32_t)bf16_rn(b) << 16);
}
__device__ inline float bflo(uint32_t u) { return __uint_as_float(u << 16); }
__device__ inline float bfhi(uint32_t u) { return __uint_as_float(u & 0xffff0000u); }

typedef __attribute__((ext_vector_type(8))) short bf16x8;
typedef __attribute__((ext_vector_type(4))) float f32x4;

// ---------------------------------------------------------------------------
// features f32 -> packed bf16x2 (one-time per call, streaming)
// ---------------------------------------------------------------------------
__global__ __launch_bounds__(256) void fcvt_kernel(
    const float4* __restrict__ in, uint2* __restrict__ out, long long n4)
{
    long long stride = (long long)gridDim.x * 256;
    for (long long i = blockIdx.x * 256LL + threadIdx.x; i < n4; i += stride) {
        float4 v = in[i];
        out[i] = make_uint2(pack2bf(v.x, v.y), pack2bf(v.z, v.w));
    }
}

// ---------------------------------------------------------------------------
// Bucketed CSR build. Bucket = dst>>10 (1024 nodes). No global atomics.
// pairs entry: (dstLocal << 22) | src   (src < 2^22, dstLocal < 1024)
// ---------------------------------------------------------------------------
#define EPB 4096   // edges per block in count/scatter passes

// pass A: per-block bucket counts -> cnt[blk][NB]; blockIdx.y = layer
__global__ __launch_bounds__(256) void bcount3_kernel(
    const int* __restrict__ d0, const int* __restrict__ d1, const int* __restrict__ d2,
    int E0, int E1, int E2, int nb0, int nb1, int nb2,
    int nblk0, int nblk1, int nblk2, int cO0, int cO1, int cO2,
    uint32_t* __restrict__ cnt)
{
    int L = blockIdx.y;
    const int* dst = L == 0 ? d0 : (L == 1 ? d1 : d2);
    int E  = L == 0 ? E0 : (L == 1 ? E1 : E2);
    int NB = L == 0 ? nb0 : (L == 1 ? nb1 : nb2);
    int nblk = L == 0 ? nblk0 : (L == 1 ? nblk1 : nblk2);
    int cO = L == 0 ? cO0 : (L == 1 ? cO1 : cO2);
    if ((int)blockIdx.x >= nblk) return;

    __shared__ uint32_t lh[256];
    int tid = threadIdx.x;
    lh[tid] = 0;
    __syncthreads();
    int base = blockIdx.x * EPB;
    for (int i = tid; i < EPB; i += 256) {
        int e = base + i;
        if (e < E) atomicAdd(&lh[((uint32_t)dst[e]) >> 10], 1u);
    }
    __syncthreads();
    uint32_t* row = cnt + cO + (size_t)blockIdx.x * NB;
    if (tid < NB) row[tid] = lh[tid];
}

// pass S1+S2(+rebase): bucket totals + per-layer scan -> bo[]; then rewrite
// cnt columns into running per-(block,bucket) bases (absorbed brebase).
__global__ __launch_bounds__(512) void bscan_kernel(
    uint32_t* __restrict__ cnt, uint32_t* __restrict__ bo,
    uint32_t* __restrict__ rowptr3,
    int nb0, int nb1, int nb2, int nblk0, int nblk1, int nblk2,
    int cO0, int cO1, int cO2, int N1, int N2, int N3, int r1, int r2)
{
    __shared__ uint32_t tot[344];
    __shared__ uint32_t bol[348];
    int t = threadIdx.x;
    int TB = nb0 + nb1 + nb2;
    int lb = 0, nblk = 0, cO = 0, NB = 0, layer = 0;
    if (t < TB) {
        if (t < nb0) { layer = 0; lb = t; nblk = nblk0; cO = cO0; NB = nb0; }
        else if (t < nb0 + nb1) { layer = 1; lb = t - nb0; nblk = nblk1; cO = cO1; NB = nb1; }
        else { layer = 2; lb = t - nb0 - nb1; nblk = nblk2; cO = cO2; NB = nb2; }
        uint32_t s = 0;
        for (int b = 0; b < nblk; ++b) s += cnt[cO + (size_t)b * NB + lb];
        tot[t] = s;
    }
    __syncthreads();
    if (t < 3) {
        int nb = t == 0 ? nb0 : (t == 1 ? nb1 : nb2);
        int g0 = t == 0 ? 0 : (t == 1 ? nb0 : nb0 + nb1);
        int gi0 = g0 + t;
        uint32_t run = 0;
        for (int i = 0; i < nb; ++i) { bol[gi0 + i] = run; run += tot[g0 + i]; }
        bol[gi0 + nb] = run;
        int rp = t == 0 ? 0 : (t == 1 ? r1 : r2);
        int N = t == 0 ? N1 : (t == 1 ? N2 : N3);
        rowptr3[rp + N] = run;
    }
    __syncthreads();
    for (int i = t; i < TB + 3; i += 512) bo[i] = bol[i];
    // absorbed brebase: each thread owns its bucket's column
    if (t < TB) {
        uint32_t base = bol[t + layer];
        for (int b = 0; b < nblk; ++b) {
            size_t ix = cO + (size_t)b * NB + lb;
            uint32_t old = cnt[ix]; cnt[ix] = base; base += old;
        }
    }
}

// pass B: scatter edges into bucket-grouped pairs; blockIdx.y = layer
__global__ __launch_bounds__(256) void bscatter3_kernel(
    const int* __restrict__ s0, const int* __restrict__ d0,
    const int* __restrict__ s1, const int* __restrict__ d1,
    const int* __restrict__ s2, const int* __restrict__ d2,
    int E0, int E1, int E2, int nb0, int nb1, int nb2,
    int nblk0, int nblk1, int nblk2, int cO0, int cO1, int cO2,
    const uint32_t* __restrict__ cnt, uint32_t* __restrict__ pairs)
{
    int L = blockIdx.y;
    const int* src = L == 0 ? s0 : (L == 1 ? s1 : s2);
    const int* dst = L == 0 ? d0 : (L == 1 ? d1 : d2);
    int E  = L == 0 ? E0 : (L == 1 ? E1 : E2);
    int NB = L == 0 ? nb0 : (L == 1 ? nb1 : nb2);
    int nblk = L == 0 ? nblk0 : (L == 1 ? nblk1 : nblk2);
    int cO = L == 0 ? cO0 : (L == 1 ? cO1 : cO2);
    uint32_t* pr = pairs + (L == 0 ? 0 : (L == 1 ? E0 : E0 + E1));
    if ((int)blockIdx.x >= nblk) return;

    __shared__ uint32_t rank[256];
    int tid = threadIdx.x;
    rank[tid] = 0;
    __syncthreads();
    const uint32_t* basep = cnt + cO + (size_t)blockIdx.x * NB;
    int base = blockIdx.x * EPB;
    for (int i = tid; i < EPB; i += 256) {
        int e = base + i;
        if (e < E) {
            uint32_t d = (uint32_t)dst[e];
            uint32_t bk = d >> 10;
            uint32_t r = atomicAdd(&rank[bk], 1u);
            uint32_t pos = basep[bk] + r;
            pr[pos] = ((d & 1023u) << 22) | (uint32_t)src[e];
        }
    }
}

// pass C: one block per bucket: LDS hist -> scan -> rowptr + fine elist fill
__global__ __launch_bounds__(256) void bfill_kernel(
    const uint32_t* __restrict__ bo, const uint32_t* __restrict__ pairs,
    int* __restrict__ elist3, uint32_t* __restrict__ rowptr3,
    int nb0, int nb1, int nb2, int N1, int N2, int N3,
    int E0, int E1, int r1, int r2)
{
    __shared__ uint32_t hist[1024];
    __shared__ uint32_t cur[1024];
    __shared__ uint32_t psum[256];
    int g = blockIdx.x, tid = threadIdx.x;
    int layer, lb, N, Eoff, rp;
    if (g < nb0) { layer = 0; lb = g; N = N1; Eoff = 0; rp = 0; }
    else if (g < nb0 + nb1) { layer = 1; lb = g - nb0; N = N2; Eoff = E0; rp = r1; }
    else { layer = 2; lb = g - nb0 - nb1; N = N3; Eoff = E0 + E1; rp = r2; }
    uint32_t off = bo[g + layer], end = bo[g + layer + 1];
    int nodeBase = lb << 10;
    int nodesIn = N - nodeBase; if (nodesIn > 1024) nodesIn = 1024;

    #pragma unroll
    for (int i = 0; i < 4; ++i) hist[tid * 4 + i] = 0;
    __syncthreads();
    for (uint32_t e = off + tid; e < end; e += 256)
        atomicAdd(&hist[pairs[Eoff + e] >> 22], 1u);
    __syncthreads();

    uint32_t x[4]; uint32_t s = 0;
    #pragma unroll
    for (int i = 0; i < 4; ++i) { x[i] = hist[tid * 4 + i]; s += x[i]; }
    psum[tid] = s; __syncthreads();
    uint32_t inc = s;
    #pragma unroll
    for (int o = 1; o < 256; o <<= 1) {
        uint32_t y = (tid >= o) ? psum[tid - o] : 0u;
        __syncthreads();
        inc += y; psum[tid] = inc;
        __syncthreads();
    }
    uint32_t run = off + inc - s;
    #pragma unroll
    for (int i = 0; i < 4; ++i) { cur[tid * 4 + i] = run; run += x[i]; }
    __syncthreads();

    for (int i = tid; i < nodesIn; i += 256)
        rowptr3[rp + nodeBase + i] = cur[i];
    __syncthreads();

    for (uint32_t e = off + tid; e < end; e += 256) {
        uint32_t pk = pairs[Eoff + e];
        uint32_t pos = atomicAdd(&cur[pk >> 22], 1u);
        elist3[Eoff + pos] = (int)(pk & 0x3FFFFFu);
    }
}

// ---------------------------------------------------------------------------
// Batched type bucketing; order3 PADDED to 128-multiples per bin (pad = -1)
// ---------------------------------------------------------------------------
__global__ __launch_bounds__(256) void count3_kernel(
    const int* __restrict__ t0, const int* __restrict__ t1, const int* __restrict__ t2,
    int n0, int n1, int n2, uint32_t* __restrict__ tcnt)
{
    __shared__ uint32_t lh[24];
    int tid = threadIdx.x;
    if (tid < 24) lh[tid] = 0;
    __syncthreads();
    int i = blockIdx.x * 256 + tid;
    if (i < n0) atomicAdd(&lh[t0[i]], 1u);
    else if (i < n0 + n1) atomicAdd(&lh[8 + t1[i - n0]], 1u);
    else if (i < n0 + n1 + n2) atomicAdd(&lh[16 + t2[i - n0 - n1]], 1u);
    __syncthreads();
    if (tid < 24 && lh[tid]) atomicAdd(&tcnt[tid], lh[tid]);
}

__global__ __launch_bounds__(256) void scan_types3_kernel(
    const uint32_t* __restrict__ tcnt, int* __restrict__ boff,
    uint32_t* __restrict__ tcur, int* __restrict__ order3, int no1p, int no2p)
{
    __shared__ int pB[27];
    __shared__ int cnts[24];
    int tid = threadIdx.x;
    if (tid == 0) {
        for (int L = 0; L < 3; ++L) {
            int a = 0;
            for (int t = 0; t < 8; ++t) {
                pB[L * 9 + t] = a;
                int c = (int)tcnt[L * 8 + t];
                cnts[L * 8 + t] = c;
                tcur[L * 8 + t] = (uint32_t)a;
                a += (c + 127) & ~127;
            }
            pB[L * 9 + 8] = a;
        }
    }
    __syncthreads();
    if (tid < 27) boff[tid] = pB[tid];
    if (tid < 24) {
        int L = tid >> 3, t = tid & 7;
        int noff = L == 0 ? 0 : (L == 1 ? no1p : no2p);
        int s = pB[L * 9 + t] + cnts[tid];
        int e2 = pB[L * 9 + t + 1];
        for (int k = s; k < e2; ++k) order3[noff + k] = -1;
    }
}

__global__ __launch_bounds__(256) void order3_kernel(
    const int* __restrict__ t0, const int* __restrict__ t1, const int* __restrict__ t2,
    int n0, int n1, int n2, uint32_t* __restrict__ tcur,
    int* __restrict__ order3, int no1p, int no2p)
{
    __shared__ uint32_t lh[24], lbase[24];
    int tid = threadIdx.x;
    if (tid < 24) lh[tid] = 0;
    __syncthreads();
    int i = blockIdx.x * 256 + tid;
    int slot = -1, idx = 0; uint32_t r = 0;
    if (i < n0) { idx = i; slot = t0[idx]; }
    else if (i < n0 + n1) { idx = i - n0; slot = 8 + t1[idx]; }
    else if (i < n0 + n1 + n2) { idx = i - n0 - n1; slot = 16 + t2[idx]; }
    if (slot >= 0) r = atomicAdd(&lh[slot], 1u);
    __syncthreads();
    if (tid < 24 && lh[tid]) lbase[tid] = atomicAdd(&tcur[tid], lh[tid]);
    __syncthreads();
    if (slot >= 0) {
        int noff = slot < 8 ? 0 : (slot < 16 ? no1p : no2p);
        order3[noff + lbase[slot] + r] = idx;
    }
}

// ---------------------------------------------------------------------------
// Weight prep: src f32 [8][128][C] (k-major) -> dst bf16 hi/lo [8][C][128]
// transposed + XOR-swizzled: chunk' = (k>>3) ^ (c&15).
// ---------------------------------------------------------------------------
__global__ __launch_bounds__(256) void prep_wt_kernel(
    const float* __restrict__ src8, ushort* __restrict__ dsthi,
    ushort* __restrict__ dstlo, int C)
{
    int t = blockIdx.x;
    const float* S = src8 + (size_t)t * 128 * C;
    ushort* DH = dsthi + (size_t)t * C * 128;
    ushort* DL = dstlo + (size_t)t * C * 128;
    for (int idx = threadIdx.x; idx < 128 * C; idx += 256) {
        int k = idx / C, c = idx % C;
        float v = S[(size_t)k * C + c];
        ushort hi = bf16_rn(v);
        ushort lo = bf16_rn(v - bf16_f(hi));
        int pos = c * 128 + ((((k >> 3) ^ (c & 15)) << 3) | (k & 7));
        DH[pos] = hi; DL[pos] = lo;
    }
}

// ---------------------------------------------------------------------------
// FUSED aggregate + MFMA GEMM (split-bf16):
//   out[n] = [relu]( mean_{src in N(n)} hin[src] @ W[t] + b[t] ) [* dropout]
// Per block: 8 waves gather+mean 128 nodes' rows (f32 acc, same lane/order as
// the old aggregate kernel -> bit-identical), pack split-bf16 into swizzled
// LDS A-tile; barrier; r7-verified MFMA path; fused epilogue.
// LDS: A 64KB + W DOUT/2 KB*... DOUT=128: 128.5KB; DOUT=64: 96.5KB.
// ---------------------------------------------------------------------------
template<int DOUT, bool RELU, bool DROP, bool OUTBF>
__global__ __launch_bounds__(512) void fused_gnn_kernel(
    const uint32_t* __restrict__ hin, const uint32_t* __restrict__ rowptr,
    const int* __restrict__ elist,
    const int* __restrict__ order, const int* __restrict__ off,
    const ushort* __restrict__ WThi, const ushort* __restrict__ WTlo,
    const float* __restrict__ bias8, void* __restrict__ houtv,
    uint32_t fk0, uint32_t fk1)
{
    __shared__ ushort AH[128 * 128];
    __shared__ ushort AL[128 * 128];
    __shared__ ushort WH[DOUT * 128];
    __shared__ ushort WL[DOUT * 128];
    __shared__ int ND[128];

    int b0 = blockIdx.x * 128;
    if (b0 >= off[8]) return;
    int t = 0;
    #pragma unroll
    for (int u = 1; u < 8; ++u) if (b0 >= off[u]) ++t;
    int tid = threadIdx.x;

    if (tid < 128) ND[tid] = order[b0 + tid];

    // stage W (pre-transposed, pre-swizzled -> straight copy)
    {
        const float4* sh = (const float4*)(WThi + (size_t)t * DOUT * 128);
        const float4* sl = (const float4*)(WTlo + (size_t)t * DOUT * 128);
        float4* dh = (float4*)WH; float4* dl = (float4*)WL;
        #pragma unroll
        for (int it = 0; it < DOUT * 16 / 512; ++it) {
            int c = it * 512 + tid;
            dh[c] = sh[c]; dl[c] = sl[c];
        }
    }
    __syncthreads();   // ND visible to all

    int wid = tid >> 6, lane = tid & 63;

    // --- gather+mean phase: wave wid owns rows wid*16..wid*16+15, 2 at a time
    {
        const uint32_t* hb = hin + lane;
        uint32_t* AHu = (uint32_t*)AH;
        uint32_t* ALu = (uint32_t*)AL;
        for (int jj = 0; jj < 8; ++jj) {
            int row0 = wid * 16 + jj * 2;
            int row1 = row0 + 1;
            int nd0 = ND[row0], nd1 = ND[row1];
            float a0x = 0.f, a0y = 0.f, a1x = 0.f, a1y = 0.f;
            uint32_t i0 = 0, e0 = 0, i1 = 0, e1 = 0, d0 = 0, d1 = 0;
            if (nd0 >= 0) { i0 = rowptr[nd0]; e0 = rowptr[nd0 + 1]; d0 = e0 - i0; }
            if (nd1 >= 0) { i1 = rowptr[nd1]; e1 = rowptr[nd1 + 1]; d1 = e1 - i1; }

            while (i0 + 4 <= e0 && i1 + 4 <= e1) {
                uint32_t u[4], w[4];
                #pragma unroll
                for (int k = 0; k < 4; ++k) u[k] = hb[(size_t)elist[i0 + k] * 64];
                #pragma unroll
                for (int k = 0; k < 4; ++k) w[k] = hb[(size_t)elist[i1 + k] * 64];
                #pragma unroll
                for (int k = 0; k < 4; ++k) { a0x += bflo(u[k]); a0y += bfhi(u[k]); }
                #pragma unroll
                for (int k = 0; k < 4; ++k) { a1x += bflo(w[k]); a1y += bfhi(w[k]); }
                i0 += 4; i1 += 4;
            }
            while (i0 + 4 <= e0) {
                uint32_t u[4];
                #pragma unroll
                for (int k = 0; k < 4; ++k) u[k] = hb[(size_t)elist[i0 + k] * 64];
                #pragma unroll
                for (int k = 0; k < 4; ++k) { a0x += bflo(u[k]); a0y += bfhi(u[k]); }
                i0 += 4;
            }
            while (i1 + 4 <= e1) {
                uint32_t w[4];
                #pragma unroll
                for (int k = 0; k < 4; ++k) w[k] = hb[(size_t)elist[i1 + k] * 64];
                #pragma unroll
                for (int k = 0; k < 4; ++k) { a1x += bflo(w[k]); a1y += bfhi(w[k]); }
                i1 += 4;
            }
            for (; i0 < e0; ++i0) {
                uint32_t u = hb[(size_t)elist[i0] * 64];
                a0x += bflo(u); a0y += bfhi(u);
            }
            for (; i1 < e1; ++i1) {
                uint32_t w = hb[(size_t)elist[i1] * 64];
                a1x += bflo(w); a1y += bfhi(w);
            }

            float sc0 = 1.0f / fmaxf((float)d0, 1.0f);
            a0x *= sc0; a0y *= sc0;
            float sc1 = 1.0f / fmaxf((float)d1, 1.0f);
            a1x *= sc1; a1y *= sc1;

            // pack split-bf16 and write to swizzled LDS A-tile.
            // lane owns feats 2l,2l+1 -> uint32 slot (l&3) of chunk (l>>2).
            ushort h0x = bf16_rn(a0x); ushort l0x = bf16_rn(a0x - bf16_f(h0x));
            ushort h0y = bf16_rn(a0y); ushort l0y = bf16_rn(a0y - bf16_f(h0y));
            int ix0 = row0 * 64 + (((lane >> 2) ^ (row0 & 15)) << 2) + (lane & 3);
            AHu[ix0] = (uint32_t)h0x | ((uint32_t)h0y << 16);
            ALu[ix0] = (uint32_t)l0x | ((uint32_t)l0y << 16);
            ushort h1x = bf16_rn(a1x); ushort l1x = bf16_rn(a1x - bf16_f(h1x));
            ushort h1y = bf16_rn(a1y); ushort l1y = bf16_rn(a1y - bf16_f(h1y));
            int ix1 = row1 * 64 + (((lane >> 2) ^ (row1 & 15)) << 2) + (lane & 3);
            AHu[ix1] = (uint32_t)h1x | ((uint32_t)h1y << 16);
            ALu[ix1] = (uint32_t)l1x | ((uint32_t)l1y << 16);
        }
    }
    __syncthreads();

    // --- MFMA phase (r7-verified path) ---
    int r15 = lane & 15, q = lane >> 4;
    constexpr int NF = DOUT / 16;
    f32x4 acc[NF];
    #pragma unroll
    for (int i = 0; i < NF; ++i) acc[i] = (f32x4){0.f, 0.f, 0.f, 0.f};

    int arow = wid * 16 + r15;
    const bf16x8* AHp = (const bf16x8*)AH;
    const bf16x8* ALp = (const bf16x8*)AL;
    const bf16x8* WHp = (const bf16x8*)WH;
    const bf16x8* WLp = (const bf16x8*)WL;

    #pragma unroll
    for (int ks = 0; ks < 4; ++ks) {
        int sch = (q + ks * 4) ^ r15;
        bf16x8 ah = AHp[arow * 16 + sch];
        bf16x8 al = ALp[arow * 16 + sch];
        #pragma unroll
        for (int nf = 0; nf < NF; ++nf) {
            int col = nf * 16 + r15;
            bf16x8 bh = WHp[col * 16 + sch];
            bf16x8 bl = WLp[col * 16 + sch];
            acc[nf] = __builtin_amdgcn_mfma_f32_16x16x32_bf16(ah, bh, acc[nf], 0, 0, 0);
            acc[nf] = __builtin_amdgcn_mfma_f32_16x16x32_bf16(ah, bl, acc[nf], 0, 0, 0);
            acc[nf] = __builtin_amdgcn_mfma_f32_16x16x32_bf16(al, bh, acc[nf], 0, 0, 0);
        }
    }

    // epilogue: C/D row = wid*16 + q*4 + r, col = nf*16 + r15
    int ndr[4];
    #pragma unroll
    for (int r = 0; r < 4; ++r) ndr[r] = ND[wid * 16 + q * 4 + r];
    const float* bptr = bias8 + (size_t)t * DOUT;

    #pragma unroll
    for (int nf = 0; nf < NF; ++nf) {
        int col = nf * 16 + r15;
        float bv = bptr[col];
        float vr[4];
        #pragma unroll
        for (int r = 0; r < 4; ++r) {
            float v = acc[nf][r] + bv;
            if (RELU) v = fmaxf(v, 0.f);
            if (DROP) {
                int nd = ndr[r] < 0 ? 0 : ndr[r];
                v *= drop_scale(fk0, fk1, (uint32_t)nd * 128u + (uint32_t)col);
            }
            vr[r] = v;
        }
        if (OUTBF) {
            uint32_t* hbo = (uint32_t*)houtv;
            #pragma unroll
            for (int r = 0; r < 4; ++r) {
                float w = __shfl_xor(vr[r], 1, 64);
                if ((lane & 1) == 0 && ndr[r] >= 0)
                    hbo[(size_t)ndr[r] * (DOUT / 2) + (col >> 1)] = pack2bf(vr[r], w);
            }
        } else {
            float* ho = (float*)houtv;
            #pragma unroll
            for (int r = 0; r < 4; ++r)
                if (ndr[r] >= 0) ho[(size_t)ndr[r] * DOUT + col] = vr[r];
        }
    }
}

// ---------------------------------------------------------------------------
// fc fusion: Wf[t] = W[t] @ fcW (128x64 f32), bf[t] = b[t] @ fcW + fcb
// ---------------------------------------------------------------------------
__global__ __launch_bounds__(256) void fuse_fc_kernel(
    const float* __restrict__ convW, const float* __restrict__ convb,
    const float* __restrict__ fcW, const float* __restrict__ fcb,
    float* __restrict__ Wf, float* __restrict__ bf)
{
    __shared__ float F[128 * 64];
    int t = blockIdx.x, tid = threadIdx.x;
    #pragma unroll
    for (int it = 0; it < 8; ++it) {
        int idx4 = (it * 256 + tid) * 4;
        *(float4*)&F[idx4] = *(const float4*)&fcW[idx4];
    }
    __syncthreads();

    int r = tid >> 1, cb = (tid & 1) * 32;
    const float* Wrow = convW + (size_t)t * 16384 + (size_t)r * 128;
    float acc[32];
    #pragma unroll
    for (int c = 0; c < 32; ++c) acc[c] = 0.f;
    for (int k = 0; k < 128; ++k) {
        float w = Wrow[k];
        #pragma unroll
        for (int c = 0; c < 32; ++c) acc[c] += w * F[k * 64 + cb + c];
    }
    float* outp = Wf + (size_t)t * 8192 + (size_t)r * 64 + cb;
    #pragma unroll
    for (int c = 0; c < 32; ++c) outp[c] = acc[c];

    if (tid < 64) {
        float a = fcb[tid];
        const float* bt = convb + (size_t)t * 128;
        for (int k = 0; k < 128; ++k) a += bt[k] * F[k * 64 + tid];
        bf[(size_t)t * 64 + tid] = a;
    }
}

// ---------------------------------------------------------------------------
extern "C" void kernel_launch(void* const* d_in, const int* in_sizes, int n_in,
                              void* d_out, int out_size, void* d_ws, size_t ws_size,
                              hipStream_t stream)
{
    const float* features = (const float*)d_in[0];
    const int*   src0 = (const int*)d_in[1];
    const int*   dst0 = (const int*)d_in[2];
    const int*   types1 = (const int*)d_in[3];
    const int*   src1 = (const int*)d_in[4];
    const int*   dst1 = (const int*)d_in[5];
    const int*   types2 = (const int*)d_in[6];
    const int*   src2 = (const int*)d_in[7];
    const int*   dst2 = (const int*)d_in[8];
    const int*   types3 = (const int*)d_in[9];
    const float* convW = (const float*)d_in[10];
    const float* convb = (const float*)d_in[11];
    const float* fcW   = (const float*)d_in[12];
    const float* fcb   = (const float*)d_in[13];

    int N0 = in_sizes[0] / 128;
    int E0 = in_sizes[1], N1 = in_sizes[3];
    int E1 = in_sizes[4], N2 = in_sizes[6];
    int E2 = in_sizes[7], N3 = in_sizes[9];
    int totalN = N1 + N2 + N3;
    int totalE = E0 + E1 + E2;
    int r1 = N1 + 1, r2 = N1 + 1 + N2 + 1;           // rowptr offsets
    int no1p = N1 + 1024, no2p = no1p + N2 + 1024;   // padded order3 offsets

    // bucket-sort geometry
    int nb0 = (N1 + 1023) >> 10, nb1 = (N2 + 1023) >> 10, nb2 = (N3 + 1023) >> 10;
    int TB = nb0 + nb1 + nb2;
    int nblk0 = (E0 + EPB - 1) / EPB, nblk1 = (E1 + EPB - 1) / EPB, nblk2 = (E2 + EPB - 1) / EPB;
    int nblkMax = nblk0 > nblk1 ? nblk0 : nblk1; if (nblk2 > nblkMax) nblkMax = nblk2;
    int cO0 = 0;
    int cO1 = cO0 + nblk0 * nb0;
    int cO2 = cO1 + nblk1 * nb1;
    int cntEntries = cO2 + nblk2 * nb2;

    char* ws = (char*)d_ws;
    size_t woff = 0;
    auto alloc = [&](size_t bytes) -> void* {
        void* p = ws + woff;
        woff = (woff + bytes + 255) & ~(size_t)255;
        return p;
    };
    // ping-pong h buffers (fused kernel reads hin while writing hout -> must
    // NOT alias). buf0 = features-bf16 (N0 rows); buf1 = N1 rows.
    uint32_t* buf0    = (uint32_t*)alloc((size_t)N0 * 64 * 4);
    uint32_t* buf1    = (uint32_t*)alloc((size_t)N1 * 64 * 4);
    uint32_t* rowptr3 = (uint32_t*)alloc((size_t)(totalN + 3) * 4);
    int*      elist3  = (int*)alloc((size_t)totalE * 4);
    uint32_t* pairs   = (uint32_t*)alloc((size_t)totalE * 4);
    int*      order3  = (int*)alloc((size_t)(totalN + 3 * 1024) * 4);
    uint32_t* cnt     = (uint32_t*)alloc((size_t)cntEntries * 4);
    uint32_t* bo      = (uint32_t*)alloc((size_t)(TB + 3) * 4);
    uint32_t* tcnt    = (uint32_t*)alloc(24 * 4);
    int*      boff    = (int*)alloc(27 * 4);
    uint32_t* tcur    = (uint32_t*)alloc(24 * 4);
    float*    Wf      = (float*)alloc((size_t)8 * 128 * 64 * 4);
    float*    bfb     = (float*)alloc((size_t)8 * 64 * 4);
    ushort*   WThi    = (ushort*)alloc((size_t)8 * 128 * 128 * 2);
    ushort*   WTlo    = (ushort*)alloc((size_t)8 * 128 * 128 * 2);
    ushort*   WfThi   = (ushort*)alloc((size_t)8 * 64 * 128 * 2);
    ushort*   WfTlo   = (ushort*)alloc((size_t)8 * 64 * 128 * 2);
    (void)ws_size; (void)n_in; (void)out_size;

    // --- one-time prep ---
    fcvt_kernel<<<4096, 256, 0, stream>>>(
        (const float4*)features, (uint2*)buf0, (long long)N0 * 32);
    prep_wt_kernel<<<8, 256, 0, stream>>>(convW, WThi, WTlo, 128);
    fuse_fc_kernel<<<8, 256, 0, stream>>>(convW, convb, fcW, fcb, Wf, bfb);
    prep_wt_kernel<<<8, 256, 0, stream>>>(Wf, WfThi, WfTlo, 64);

    // --- bucketed CSR build (no global atomics) ---
    bcount3_kernel<<<dim3(nblkMax, 3), 256, 0, stream>>>(
        dst0, dst1, dst2, E0, E1, E2, nb0, nb1, nb2,
        nblk0, nblk1, nblk2, cO0, cO1, cO2, cnt);
    bscan_kernel<<<1, 512, 0, stream>>>(cnt, bo, rowptr3,
        nb0, nb1, nb2, nblk0, nblk1, nblk2, cO0, cO1, cO2, N1, N2, N3, r1, r2);
    bscatter3_kernel<<<dim3(nblkMax, 3), 256, 0, stream>>>(
        src0, dst0, src1, dst1, src2, dst2, E0, E1, E2, nb0, nb1, nb2,
        nblk0, nblk1, nblk2, cO0, cO1, cO2, cnt, pairs);
    bfill_kernel<<<TB, 256, 0, stream>>>(bo, pairs, elist3, rowptr3,
        nb0, nb1, nb2, N1, N2, N3, E0, E1, r1, r2);

    // --- batched type bucketing (padded bins) ---
    hipMemsetAsync(tcnt, 0, 24 * 4, stream);
    int nblkT = (totalN + 255) / 256;
    count3_kernel<<<nblkT, 256, 0, stream>>>(types1, types2, types3, N1, N2, N3, tcnt);
    scan_types3_kernel<<<1, 256, 0, stream>>>(tcnt, boff, tcur, order3, no1p, no2p);
    order3_kernel<<<nblkT, 256, 0, stream>>>(
        types1, types2, types3, N1, N2, N3, tcur, order3, no1p, no2p);

    // fold-in keys
    uint32_t fk1a, fk1b, fk2a, fk2b;
    tf2x32(0u, 42u, 0u, 1u, &fk1a, &fk1b);
    tf2x32(0u, 42u, 0u, 2u, &fk2a, &fk2b);

    // --- layer 0: buf0 -> buf1 ---
    fused_gnn_kernel<128, true, true, true><<<(N1 + 127) / 128 + 8, 512, 0, stream>>>(
        buf0, rowptr3, elist3, order3, boff, WThi, WTlo, convb, buf1, fk1a, fk1b);

    // --- layer 1: buf1 -> buf0 ---
    fused_gnn_kernel<128, true, true, true><<<(N2 + 127) / 128 + 8, 512, 0, stream>>>(
        buf1, rowptr3 + r1, elist3 + E0, order3 + no1p, boff + 9,
        WThi, WTlo, convb, buf0, fk2a, fk2b);

    // --- layer 2 (fc folded): buf0 -> d_out (f32) ---
    fused_gnn_kernel<64, false, false, false><<<(N3 + 127) / 128 + 8, 512, 0, stream>>>(
        buf0, rowptr3 + r2, elist3 + E0 + E1, order3 + no2p, boff + 18,
        WfThi, WfTlo, bfb, d_out, 0u, 0u);
}

// Round 10
// 687.205 us; speedup vs baseline: 1.3975x; 1.3975x over previous
//
#include <hip/hip_runtime.h>
#include <cstdint>
#include <cstddef>

// ---------------------------------------------------------------------------
// JAX threefry2x32 (20 rounds). fold_in(key(42), i) = threefry((0,42),(0,i))
// partitionable 32-bit random_bits: bits = o0 ^ o1 (XOR-fold)   [validated r2]
// uniform: u = bitcast((bits>>9)|0x3f800000) - 1.0f ; keep iff u < 0.9f
// ---------------------------------------------------------------------------
__host__ __device__ inline void tf2x32(uint32_t k0, uint32_t k1,
                                       uint32_t x0, uint32_t x1,
                                       uint32_t* o0, uint32_t* o1)
{
    uint32_t ks2 = k0 ^ k1 ^ 0x1BD11BDAu;
    x0 += k0; x1 += k1;
#define TF_R(r) do { x0 += x1; x1 = (x1 << (r)) | (x1 >> (32 - (r))); x1 ^= x0; } while (0)
    TF_R(13); TF_R(15); TF_R(26); TF_R(6);
    x0 += k1;  x1 += ks2 + 1u;
    TF_R(17); TF_R(29); TF_R(16); TF_R(24);
    x0 += ks2; x1 += k0 + 2u;
    TF_R(13); TF_R(15); TF_R(26); TF_R(6);
    x0 += k0;  x1 += k1 + 3u;
    TF_R(17); TF_R(29); TF_R(16); TF_R(24);
    x0 += k1;  x1 += ks2 + 4u;
    TF_R(13); TF_R(15); TF_R(26); TF_R(6);
    x0 += ks2; x1 += k0 + 5u;
#undef TF_R
    *o0 = x0; *o1 = x1;
}

__device__ inline float drop_scale(uint32_t fk0, uint32_t fk1, uint32_t idx)
{
    uint32_t o0, o1;
    tf2x32(fk0, fk1, 0u, idx, &o0, &o1);
    uint32_t bits = o0 ^ o1;
    float u = __uint_as_float((bits >> 9) | 0x3f800000u) - 1.0f;
    return (u < 0.9f) ? (1.0f / 0.9f) : 0.0f;
}

// bf16 helpers (round-to-nearest-even)
__device__ inline ushort bf16_rn(float f)
{
    uint32_t u = __float_as_uint(f);
    u += 0x7fffu + ((u >> 16) & 1u);
    return (ushort)(u >> 16);
}
__device__ inline float bf16_f(ushort h) { return __uint_as_float(((uint32_t)h) << 16); }
__device__ inline uint32_t pack2bf(float a, float b)
{
    return (uint32_t)bf16_rn(a) | ((uint32_t)bf16_rn(b) << 16);
}
__device__ inline float bflo(uint32_t u) { return __uint_as_float(u << 16); }
__device__ inline float bfhi(uint32_t u) { return __uint_as_float(u & 0xffff0000u); }

typedef __attribute__((ext_vector_type(8))) short bf16x8;
typedef __attribute__((ext_vector_type(4))) float f32x4;

// ---------------------------------------------------------------------------
// features f32 -> packed bf16x2 (one-time per call, streaming)
// ---------------------------------------------------------------------------
__global__ __launch_bounds__(256) void fcvt_kernel(
    const float4* __restrict__ in, uint2* __restrict__ out, long long n4)
{
    long long stride = (long long)gridDim.x * 256;
    for (long long i = blockIdx.x * 256LL + threadIdx.x; i < n4; i += stride) {
        float4 v = in[i];
        out[i] = make_uint2(pack2bf(v.x, v.y), pack2bf(v.z, v.w));
    }
}

// ---------------------------------------------------------------------------
// Bucketed CSR build. Bucket = dst>>10 (1024 nodes). No global atomics.
// pairs entry: (dstLocal << 22) | src   (src < 2^22, dstLocal < 1024)
// ---------------------------------------------------------------------------
#define EPB 4096   // edges per block in count/scatter passes

// pass A: per-block bucket counts -> cnt[blk][NB]; blockIdx.y = layer
__global__ __launch_bounds__(256) void bcount3_kernel(
    const int* __restrict__ d0, const int* __restrict__ d1, const int* __restrict__ d2,
    int E0, int E1, int E2, int nb0, int nb1, int nb2,
    int nblk0, int nblk1, int nblk2, int cO0, int cO1, int cO2,
    uint32_t* __restrict__ cnt)
{
    int L = blockIdx.y;
    const int* dst = L == 0 ? d0 : (L == 1 ? d1 : d2);
    int E  = L == 0 ? E0 : (L == 1 ? E1 : E2);
    int NB = L == 0 ? nb0 : (L == 1 ? nb1 : nb2);
    int nblk = L == 0 ? nblk0 : (L == 1 ? nblk1 : nblk2);
    int cO = L == 0 ? cO0 : (L == 1 ? cO1 : cO2);
    if ((int)blockIdx.x >= nblk) return;

    __shared__ uint32_t lh[256];
    int tid = threadIdx.x;
    lh[tid] = 0;
    __syncthreads();
    int base = blockIdx.x * EPB;
    for (int i = tid; i < EPB; i += 256) {
        int e = base + i;
        if (e < E) atomicAdd(&lh[((uint32_t)dst[e]) >> 10], 1u);
    }
    __syncthreads();
    uint32_t* row = cnt + cO + (size_t)blockIdx.x * NB;
    if (tid < NB) row[tid] = lh[tid];
}

// pass S1+S2(+rebase): bucket totals + per-layer scan -> bo[]; then rewrite
// cnt columns into running per-(block,bucket) bases (absorbed brebase).
__global__ __launch_bounds__(512) void bscan_kernel(
    uint32_t* __restrict__ cnt, uint32_t* __restrict__ bo,
    uint32_t* __restrict__ rowptr3,
    int nb0, int nb1, int nb2, int nblk0, int nblk1, int nblk2,
    int cO0, int cO1, int cO2, int N1, int N2, int N3, int r1, int r2)
{
    __shared__ uint32_t tot[344];
    __shared__ uint32_t bol[348];
    int t = threadIdx.x;
    int TB = nb0 + nb1 + nb2;
    int lb = 0, nblk = 0, cO = 0, NB = 0, layer = 0;
    if (t < TB) {
        if (t < nb0) { layer = 0; lb = t; nblk = nblk0; cO = cO0; NB = nb0; }
        else if (t < nb0 + nb1) { layer = 1; lb = t - nb0; nblk = nblk1; cO = cO1; NB = nb1; }
        else { layer = 2; lb = t - nb0 - nb1; nblk = nblk2; cO = cO2; NB = nb2; }
        uint32_t s = 0;
        for (int b = 0; b < nblk; ++b) s += cnt[cO + (size_t)b * NB + lb];
        tot[t] = s;
    }
    __syncthreads();
    if (t < 3) {
        int nb = t == 0 ? nb0 : (t == 1 ? nb1 : nb2);
        int g0 = t == 0 ? 0 : (t == 1 ? nb0 : nb0 + nb1);
        int gi0 = g0 + t;
        uint32_t run = 0;
        for (int i = 0; i < nb; ++i) { bol[gi0 + i] = run; run += tot[g0 + i]; }
        bol[gi0 + nb] = run;
        int rp = t == 0 ? 0 : (t == 1 ? r1 : r2);
        int N = t == 0 ? N1 : (t == 1 ? N2 : N3);
        rowptr3[rp + N] = run;
    }
    __syncthreads();
    for (int i = t; i < TB + 3; i += 512) bo[i] = bol[i];
    // absorbed brebase: each thread owns its bucket's column
    if (t < TB) {
        uint32_t base = bol[t + layer];
        for (int b = 0; b < nblk; ++b) {
            size_t ix = cO + (size_t)b * NB + lb;
            uint32_t old = cnt[ix]; cnt[ix] = base; base += old;
        }
    }
}

// pass B: scatter edges into bucket-grouped pairs; blockIdx.y = layer
__global__ __launch_bounds__(256) void bscatter3_kernel(
    const int* __restrict__ s0, const int* __restrict__ d0,
    const int* __restrict__ s1, const int* __restrict__ d1,
    const int* __restrict__ s2, const int* __restrict__ d2,
    int E0, int E1, int E2, int nb0, int nb1, int nb2,
    int nblk0, int nblk1, int nblk2, int cO0, int cO1, int cO2,
    const uint32_t* __restrict__ cnt, uint32_t* __restrict__ pairs)
{
    int L = blockIdx.y;
    const int* src = L == 0 ? s0 : (L == 1 ? s1 : s2);
    const int* dst = L == 0 ? d0 : (L == 1 ? d1 : d2);
    int E  = L == 0 ? E0 : (L == 1 ? E1 : E2);
    int NB = L == 0 ? nb0 : (L == 1 ? nb1 : nb2);
    int nblk = L == 0 ? nblk0 : (L == 1 ? nblk1 : nblk2);
    int cO = L == 0 ? cO0 : (L == 1 ? cO1 : cO2);
    uint32_t* pr = pairs + (L == 0 ? 0 : (L == 1 ? E0 : E0 + E1));
    if ((int)blockIdx.x >= nblk) return;

    __shared__ uint32_t rank[256];
    int tid = threadIdx.x;
    rank[tid] = 0;
    __syncthreads();
    const uint32_t* basep = cnt + cO + (size_t)blockIdx.x * NB;
    int base = blockIdx.x * EPB;
    for (int i = tid; i < EPB; i += 256) {
        int e = base + i;
        if (e < E) {
            uint32_t d = (uint32_t)dst[e];
            uint32_t bk = d >> 10;
            uint32_t r = atomicAdd(&rank[bk], 1u);
            uint32_t pos = basep[bk] + r;
            pr[pos] = ((d & 1023u) << 22) | (uint32_t)src[e];
        }
    }
}

// pass C: one block per bucket: LDS hist -> scan -> rowptr + fine elist fill
__global__ __launch_bounds__(256) void bfill_kernel(
    const uint32_t* __restrict__ bo, const uint32_t* __restrict__ pairs,
    int* __restrict__ elist3, uint32_t* __restrict__ rowptr3,
    int nb0, int nb1, int nb2, int N1, int N2, int N3,
    int E0, int E1, int r1, int r2)
{
    __shared__ uint32_t hist[1024];
    __shared__ uint32_t cur[1024];
    __shared__ uint32_t psum[256];
    int g = blockIdx.x, tid = threadIdx.x;
    int layer, lb, N, Eoff, rp;
    if (g < nb0) { layer = 0; lb = g; N = N1; Eoff = 0; rp = 0; }
    else if (g < nb0 + nb1) { layer = 1; lb = g - nb0; N = N2; Eoff = E0; rp = r1; }
    else { layer = 2; lb = g - nb0 - nb1; N = N3; Eoff = E0 + E1; rp = r2; }
    uint32_t off = bo[g + layer], end = bo[g + layer + 1];
    int nodeBase = lb << 10;
    int nodesIn = N - nodeBase; if (nodesIn > 1024) nodesIn = 1024;

    #pragma unroll
    for (int i = 0; i < 4; ++i) hist[tid * 4 + i] = 0;
    __syncthreads();
    for (uint32_t e = off + tid; e < end; e += 256)
        atomicAdd(&hist[pairs[Eoff + e] >> 22], 1u);
    __syncthreads();

    uint32_t x[4]; uint32_t s = 0;
    #pragma unroll
    for (int i = 0; i < 4; ++i) { x[i] = hist[tid * 4 + i]; s += x[i]; }
    psum[tid] = s; __syncthreads();
    uint32_t inc = s;
    #pragma unroll
    for (int o = 1; o < 256; o <<= 1) {
        uint32_t y = (tid >= o) ? psum[tid - o] : 0u;
        __syncthreads();
        inc += y; psum[tid] = inc;
        __syncthreads();
    }
    uint32_t run = off + inc - s;
    #pragma unroll
    for (int i = 0; i < 4; ++i) { cur[tid * 4 + i] = run; run += x[i]; }
    __syncthreads();

    for (int i = tid; i < nodesIn; i += 256)
        rowptr3[rp + nodeBase + i] = cur[i];
    __syncthreads();

    for (uint32_t e = off + tid; e < end; e += 256) {
        uint32_t pk = pairs[Eoff + e];
        uint32_t pos = atomicAdd(&cur[pk >> 22], 1u);
        elist3[Eoff + pos] = (int)(pk & 0x3FFFFFu);
    }
}

// ---------------------------------------------------------------------------
// Batched type bucketing; order3 PADDED to 128-multiples per bin (pad = -1)
// ---------------------------------------------------------------------------
__global__ __launch_bounds__(256) void count3_kernel(
    const int* __restrict__ t0, const int* __restrict__ t1, const int* __restrict__ t2,
    int n0, int n1, int n2, uint32_t* __restrict__ tcnt)
{
    __shared__ uint32_t lh[24];
    int tid = threadIdx.x;
    if (tid < 24) lh[tid] = 0;
    __syncthreads();
    int i = blockIdx.x * 256 + tid;
    if (i < n0) atomicAdd(&lh[t0[i]], 1u);
    else if (i < n0 + n1) atomicAdd(&lh[8 + t1[i - n0]], 1u);
    else if (i < n0 + n1 + n2) atomicAdd(&lh[16 + t2[i - n0 - n1]], 1u);
    __syncthreads();
    if (tid < 24 && lh[tid]) atomicAdd(&tcnt[tid], lh[tid]);
}

__global__ __launch_bounds__(256) void scan_types3_kernel(
    const uint32_t* __restrict__ tcnt, int* __restrict__ boff,
    uint32_t* __restrict__ tcur, int* __restrict__ order3, int no1p, int no2p)
{
    __shared__ int pB[27];
    __shared__ int cnts[24];
    int tid = threadIdx.x;
    if (tid == 0) {
        for (int L = 0; L < 3; ++L) {
            int a = 0;
            for (int t = 0; t < 8; ++t) {
                pB[L * 9 + t] = a;
                int c = (int)tcnt[L * 8 + t];
                cnts[L * 8 + t] = c;
                tcur[L * 8 + t] = (uint32_t)a;
                a += (c + 127) & ~127;
            }
            pB[L * 9 + 8] = a;
        }
    }
    __syncthreads();
    if (tid < 27) boff[tid] = pB[tid];
    if (tid < 24) {
        int L = tid >> 3, t = tid & 7;
        int noff = L == 0 ? 0 : (L == 1 ? no1p : no2p);
        int s = pB[L * 9 + t] + cnts[tid];
        int e2 = pB[L * 9 + t + 1];
        for (int k = s; k < e2; ++k) order3[noff + k] = -1;
    }
}

__global__ __launch_bounds__(256) void order3_kernel(
    const int* __restrict__ t0, const int* __restrict__ t1, const int* __restrict__ t2,
    int n0, int n1, int n2, uint32_t* __restrict__ tcur,
    int* __restrict__ order3, int no1p, int no2p)
{
    __shared__ uint32_t lh[24], lbase[24];
    int tid = threadIdx.x;
    if (tid < 24) lh[tid] = 0;
    __syncthreads();
    int i = blockIdx.x * 256 + tid;
    int slot = -1, idx = 0; uint32_t r = 0;
    if (i < n0) { idx = i; slot = t0[idx]; }
    else if (i < n0 + n1) { idx = i - n0; slot = 8 + t1[idx]; }
    else if (i < n0 + n1 + n2) { idx = i - n0 - n1; slot = 16 + t2[idx]; }
    if (slot >= 0) r = atomicAdd(&lh[slot], 1u);
    __syncthreads();
    if (tid < 24 && lh[tid]) lbase[tid] = atomicAdd(&tcur[tid], lh[tid]);
    __syncthreads();
    if (slot >= 0) {
        int noff = slot < 8 ? 0 : (slot < 16 ? no1p : no2p);
        order3[noff + lbase[slot] + r] = idx;
    }
}

// ---------------------------------------------------------------------------
// Gather-aggregate: 2 nodes per wave, fused 8+8-unrolled main loop -> 16
// outstanding gathers. f32 accumulate; bf16 hi/lo out.
// ---------------------------------------------------------------------------
__global__ __launch_bounds__(256) void aggregate_kernel(
    const uint32_t* __restrict__ hbf, const uint32_t* __restrict__ rowptr,
    const int* __restrict__ elist, uint32_t* __restrict__ agghi,
    uint32_t* __restrict__ agglo, int nout)
{
    int wid = threadIdx.x >> 6, lane = threadIdx.x & 63;
    int n0 = blockIdx.x * 8 + wid * 2;
    if (n0 >= nout) return;
    int n1 = n0 + 1;
    bool v1 = (n1 < nout);
    uint32_t b0 = rowptr[n0], e0 = rowptr[n0 + 1];
    uint32_t b1 = v1 ? rowptr[n1] : 0u, e1 = v1 ? rowptr[n1 + 1] : 0u;
    const uint32_t* base = hbf + lane;
    float a0x = 0.f, a0y = 0.f, a1x = 0.f, a1y = 0.f;
    uint32_t i0 = b0, i1 = b1;

    while (i0 + 8 <= e0 && i1 + 8 <= e1) {
        uint32_t u[8], w[8];
        #pragma unroll
        for (int k = 0; k < 8; ++k) u[k] = base[(size_t)elist[i0 + k] * 64];
        #pragma unroll
        for (int k = 0; k < 8; ++k) w[k] = base[(size_t)elist[i1 + k] * 64];
        #pragma unroll
        for (int k = 0; k < 8; ++k) { a0x += bflo(u[k]); a0y += bfhi(u[k]); }
        #pragma unroll
        for (int k = 0; k < 8; ++k) { a1x += bflo(w[k]); a1y += bfhi(w[k]); }
        i0 += 8; i1 += 8;
    }
    while (i0 + 4 <= e0 && i1 + 4 <= e1) {
        uint32_t u[4], w[4];
        #pragma unroll
        for (int k = 0; k < 4; ++k) u[k] = base[(size_t)elist[i0 + k] * 64];
        #pragma unroll
        for (int k = 0; k < 4; ++k) w[k] = base[(size_t)elist[i1 + k] * 64];
        #pragma unroll
        for (int k = 0; k < 4; ++k) { a0x += bflo(u[k]); a0y += bfhi(u[k]); }
        #pragma unroll
        for (int k = 0; k < 4; ++k) { a1x += bflo(w[k]); a1y += bfhi(w[k]); }
        i0 += 4; i1 += 4;
    }
    while (i0 + 4 <= e0) {
        uint32_t u[4];
        #pragma unroll
        for (int k = 0; k < 4; ++k) u[k] = base[(size_t)elist[i0 + k] * 64];
        #pragma unroll
        for (int k = 0; k < 4; ++k) { a0x += bflo(u[k]); a0y += bfhi(u[k]); }
        i0 += 4;
    }
    while (i1 + 4 <= e1) {
        uint32_t w[4];
        #pragma unroll
        for (int k = 0; k < 4; ++k) w[k] = base[(size_t)elist[i1 + k] * 64];
        #pragma unroll
        for (int k = 0; k < 4; ++k) { a1x += bflo(w[k]); a1y += bfhi(w[k]); }
        i1 += 4;
    }
    for (; i0 < e0; ++i0) {
        uint32_t u = base[(size_t)elist[i0] * 64];
        a0x += bflo(u); a0y += bfhi(u);
    }
    for (; i1 < e1; ++i1) {
        uint32_t w = base[(size_t)elist[i1] * 64];
        a1x += bflo(w); a1y += bfhi(w);
    }

    float sc0 = 1.0f / fmaxf((float)(e0 - b0), 1.0f);
    a0x *= sc0; a0y *= sc0;
    ushort hx = bf16_rn(a0x); ushort lx = bf16_rn(a0x - bf16_f(hx));
    ushort hy = bf16_rn(a0y); ushort ly = bf16_rn(a0y - bf16_f(hy));
    agghi[(size_t)n0 * 64 + lane] = (uint32_t)hx | ((uint32_t)hy << 16);
    agglo[(size_t)n0 * 64 + lane] = (uint32_t)lx | ((uint32_t)ly << 16);
    if (v1) {
        float sc1 = 1.0f / fmaxf((float)(e1 - b1), 1.0f);
        a1x *= sc1; a1y *= sc1;
        ushort hx1 = bf16_rn(a1x); ushort lx1 = bf16_rn(a1x - bf16_f(hx1));
        ushort hy1 = bf16_rn(a1y); ushort ly1 = bf16_rn(a1y - bf16_f(hy1));
        agghi[(size_t)n1 * 64 + lane] = (uint32_t)hx1 | ((uint32_t)hy1 << 16);
        agglo[(size_t)n1 * 64 + lane] = (uint32_t)lx1 | ((uint32_t)ly1 << 16);
    }
}

// ---------------------------------------------------------------------------
// Weight prep: src f32 [8][128][C] (k-major) -> dst bf16 hi/lo [8][C][128]
// transposed + XOR-swizzled: chunk' = (k>>3) ^ (c&15).
// ---------------------------------------------------------------------------
__global__ __launch_bounds__(256) void prep_wt_kernel(
    const float* __restrict__ src8, ushort* __restrict__ dsthi,
    ushort* __restrict__ dstlo, int C)
{
    int t = blockIdx.x;
    const float* S = src8 + (size_t)t * 128 * C;
    ushort* DH = dsthi + (size_t)t * C * 128;
    ushort* DL = dstlo + (size_t)t * C * 128;
    for (int idx = threadIdx.x; idx < 128 * C; idx += 256) {
        int k = idx / C, c = idx % C;
        float v = S[(size_t)k * C + c];
        ushort hi = bf16_rn(v);
        ushort lo = bf16_rn(v - bf16_f(hi));
        int pos = c * 128 + ((((k >> 3) ^ (c & 15)) << 3) | (k & 7));
        DH[pos] = hi; DL[pos] = lo;
    }
}

// ---------------------------------------------------------------------------
// MFMA GEMM (split-bf16): out[n] = [relu](agg[n] @ W[t] + b[t]) [* dropout]
// A fragments loaded DIRECTLY from global (no cross-lane reuse -> no LDS);
// only W (+ND) staged in LDS: 64.5KB @DOUT=128 -> 2 blocks/CU, 4 waves/SIMD.
// ---------------------------------------------------------------------------
template<int DOUT, bool RELU, bool DROP, bool OUTBF>
__global__ __launch_bounds__(512) void mfma_gemm_kernel(
    const uint32_t* __restrict__ agghi, const uint32_t* __restrict__ agglo,
    const int* __restrict__ order, const int* __restrict__ off,
    const ushort* __restrict__ WThi, const ushort* __restrict__ WTlo,
    const float* __restrict__ bias8, void* __restrict__ houtv,
    uint32_t fk0, uint32_t fk1)
{
    __shared__ ushort WH[DOUT * 128];
    __shared__ ushort WL[DOUT * 128];
    __shared__ int ND[128];

    int b0 = blockIdx.x * 128;
    if (b0 >= off[8]) return;
    int t = 0;
    #pragma unroll
    for (int u = 1; u < 8; ++u) if (b0 >= off[u]) ++t;
    int tid = threadIdx.x;

    if (tid < 128) ND[tid] = order[b0 + tid];

    // stage W (pre-transposed, pre-swizzled -> straight copy)
    {
        const float4* sh = (const float4*)(WThi + (size_t)t * DOUT * 128);
        const float4* sl = (const float4*)(WTlo + (size_t)t * DOUT * 128);
        float4* dh = (float4*)WH; float4* dl = (float4*)WL;
        #pragma unroll
        for (int it = 0; it < DOUT * 16 / 512; ++it) {
            int c = it * 512 + tid;
            dh[c] = sh[c]; dl[c] = sl[c];
        }
    }
    __syncthreads();

    int wid = tid >> 6, lane = tid & 63;
    int r15 = lane & 15, q = lane >> 4;
    int arow = wid * 16 + r15;
    int nd_a = ND[arow];

    // A fragments straight from global (agg is L3-resident)
    const bf16x8* gh = (const bf16x8*)agghi;
    const bf16x8* gl = (const bf16x8*)agglo;
    bf16x8 zero8 = (bf16x8){0, 0, 0, 0, 0, 0, 0, 0};
    bf16x8 ahv[4], alv[4];
    {
        size_t rowb = (size_t)(nd_a < 0 ? 0 : nd_a) * 16;
        #pragma unroll
        for (int ks = 0; ks < 4; ++ks) {
            size_t ix = rowb + (q + ks * 4);
            ahv[ks] = (nd_a >= 0) ? gh[ix] : zero8;
            alv[ks] = (nd_a >= 0) ? gl[ix] : zero8;
        }
    }

    constexpr int NF = DOUT / 16;
    f32x4 acc[NF];
    #pragma unroll
    for (int i = 0; i < NF; ++i) acc[i] = (f32x4){0.f, 0.f, 0.f, 0.f};

    const bf16x8* WHp = (const bf16x8*)WH;
    const bf16x8* WLp = (const bf16x8*)WL;

    #pragma unroll
    for (int ks = 0; ks < 4; ++ks) {
        int sch = (q + ks * 4) ^ r15;
        bf16x8 ah = ahv[ks];
        bf16x8 al = alv[ks];
        #pragma unroll
        for (int nf = 0; nf < NF; ++nf) {
            int col = nf * 16 + r15;
            bf16x8 bh = WHp[col * 16 + sch];
            bf16x8 bl = WLp[col * 16 + sch];
            acc[nf] = __builtin_amdgcn_mfma_f32_16x16x32_bf16(ah, bh, acc[nf], 0, 0, 0);
            acc[nf] = __builtin_amdgcn_mfma_f32_16x16x32_bf16(ah, bl, acc[nf], 0, 0, 0);
            acc[nf] = __builtin_amdgcn_mfma_f32_16x16x32_bf16(al, bh, acc[nf], 0, 0, 0);
        }
    }

    // epilogue: C/D row = wid*16 + q*4 + r, col = nf*16 + r15
    int ndr[4];
    #pragma unroll
    for (int r = 0; r < 4; ++r) ndr[r] = ND[wid * 16 + q * 4 + r];
    const float* bptr = bias8 + (size_t)t * DOUT;

    #pragma unroll
    for (int nf = 0; nf < NF; ++nf) {
        int col = nf * 16 + r15;
        float bv = bptr[col];
        float vr[4];
        #pragma unroll
        for (int r = 0; r < 4; ++r) {
            float v = acc[nf][r] + bv;
            if (RELU) v = fmaxf(v, 0.f);
            if (DROP) {
                int nd = ndr[r] < 0 ? 0 : ndr[r];
                v *= drop_scale(fk0, fk1, (uint32_t)nd * 128u + (uint32_t)col);
            }
            vr[r] = v;
        }
        if (OUTBF) {
            uint32_t* hb = (uint32_t*)houtv;
            #pragma unroll
            for (int r = 0; r < 4; ++r) {
                float w = __shfl_xor(vr[r], 1, 64);
                if ((lane & 1) == 0 && ndr[r] >= 0)
                    hb[(size_t)ndr[r] * (DOUT / 2) + (col >> 1)] = pack2bf(vr[r], w);
            }
        } else {
            float* ho = (float*)houtv;
            #pragma unroll
            for (int r = 0; r < 4; ++r)
                if (ndr[r] >= 0) ho[(size_t)ndr[r] * DOUT + col] = vr[r];
        }
    }
}

// ---------------------------------------------------------------------------
// fc fusion: Wf[t] = W[t] @ fcW (128x64 f32), bf[t] = b[t] @ fcW + fcb
// ---------------------------------------------------------------------------
__global__ __launch_bounds__(256) void fuse_fc_kernel(
    const float* __restrict__ convW, const float* __restrict__ convb,
    const float* __restrict__ fcW, const float* __restrict__ fcb,
    float* __restrict__ Wf, float* __restrict__ bf)
{
    __shared__ float F[128 * 64];
    int t = blockIdx.x, tid = threadIdx.x;
    #pragma unroll
    for (int it = 0; it < 8; ++it) {
        int idx4 = (it * 256 + tid) * 4;
        *(float4*)&F[idx4] = *(const float4*)&fcW[idx4];
    }
    __syncthreads();

    int r = tid >> 1, cb = (tid & 1) * 32;
    const float* Wrow = convW + (size_t)t * 16384 + (size_t)r * 128;
    float acc[32];
    #pragma unroll
    for (int c = 0; c < 32; ++c) acc[c] = 0.f;
    for (int k = 0; k < 128; ++k) {
        float w = Wrow[k];
        #pragma unroll
        for (int c = 0; c < 32; ++c) acc[c] += w * F[k * 64 + cb + c];
    }
    float* outp = Wf + (size_t)t * 8192 + (size_t)r * 64 + cb;
    #pragma unroll
    for (int c = 0; c < 32; ++c) outp[c] = acc[c];

    if (tid < 64) {
        float a = fcb[tid];
        const float* bt = convb + (size_t)t * 128;
        for (int k = 0; k < 128; ++k) a += bt[k] * F[k * 64 + tid];
        bf[(size_t)t * 64 + tid] = a;
    }
}

// ---------------------------------------------------------------------------
extern "C" void kernel_launch(void* const* d_in, const int* in_sizes, int n_in,
                              void* d_out, int out_size, void* d_ws, size_t ws_size,
                              hipStream_t stream)
{
    const float* features = (const float*)d_in[0];
    const int*   src0 = (const int*)d_in[1];
    const int*   dst0 = (const int*)d_in[2];
    const int*   types1 = (const int*)d_in[3];
    const int*   src1 = (const int*)d_in[4];
    const int*   dst1 = (const int*)d_in[5];
    const int*   types2 = (const int*)d_in[6];
    const int*   src2 = (const int*)d_in[7];
    const int*   dst2 = (const int*)d_in[8];
    const int*   types3 = (const int*)d_in[9];
    const float* convW = (const float*)d_in[10];
    const float* convb = (const float*)d_in[11];
    const float* fcW   = (const float*)d_in[12];
    const float* fcb   = (const float*)d_in[13];

    int N0 = in_sizes[0] / 128;
    int E0 = in_sizes[1], N1 = in_sizes[3];
    int E1 = in_sizes[4], N2 = in_sizes[6];
    int E2 = in_sizes[7], N3 = in_sizes[9];
    int totalN = N1 + N2 + N3;
    int totalE = E0 + E1 + E2;
    int r1 = N1 + 1, r2 = N1 + 1 + N2 + 1;           // rowptr offsets
    int no1p = N1 + 1024, no2p = no1p + N2 + 1024;   // padded order3 offsets
    int maxN = N1 > N2 ? N1 : N2; if (N3 > maxN) maxN = N3;

    // bucket-sort geometry
    int nb0 = (N1 + 1023) >> 10, nb1 = (N2 + 1023) >> 10, nb2 = (N3 + 1023) >> 10;
    int TB = nb0 + nb1 + nb2;
    int nblk0 = (E0 + EPB - 1) / EPB, nblk1 = (E1 + EPB - 1) / EPB, nblk2 = (E2 + EPB - 1) / EPB;
    int nblkMax = nblk0 > nblk1 ? nblk0 : nblk1; if (nblk2 > nblkMax) nblkMax = nblk2;
    int cO0 = 0;
    int cO1 = cO0 + nblk0 * nb0;
    int cO2 = cO1 + nblk1 * nb1;
    int cntEntries = cO2 + nblk2 * nb2;

    char* ws = (char*)d_ws;
    size_t woff = 0;
    auto alloc = [&](size_t bytes) -> void* {
        void* p = ws + woff;
        woff = (woff + bytes + 255) & ~(size_t)255;
        return p;
    };
    uint32_t* fbf     = (uint32_t*)alloc((size_t)N0 * 64 * 4);    // packed bf16 features
    uint32_t* hbf     = fbf;                                      // alias: h after L0 agg
    uint32_t* aggHi   = (uint32_t*)alloc((size_t)maxN * 64 * 4);
    uint32_t* pairs   = aggHi;                                    // alias: dead before agg
    uint32_t* aggLo   = (uint32_t*)alloc((size_t)maxN * 64 * 4);
    uint32_t* rowptr3 = (uint32_t*)alloc((size_t)(totalN + 3) * 4);
    int*      elist3  = (int*)alloc((size_t)totalE * 4);
    int*      order3  = (int*)alloc((size_t)(totalN + 3 * 1024) * 4);
    uint32_t* cnt     = (uint32_t*)alloc((size_t)cntEntries * 4);
    uint32_t* bo      = (uint32_t*)alloc((size_t)(TB + 3) * 4);
    uint32_t* tcnt    = (uint32_t*)alloc(24 * 4);
    int*      boff    = (int*)alloc(27 * 4);
    uint32_t* tcur    = (uint32_t*)alloc(24 * 4);
    float*    Wf      = (float*)alloc((size_t)8 * 128 * 64 * 4);
    float*    bfb     = (float*)alloc((size_t)8 * 64 * 4);
    ushort*   WThi    = (ushort*)alloc((size_t)8 * 128 * 128 * 2);
    ushort*   WTlo    = (ushort*)alloc((size_t)8 * 128 * 128 * 2);
    ushort*   WfThi   = (ushort*)alloc((size_t)8 * 64 * 128 * 2);
    ushort*   WfTlo   = (ushort*)alloc((size_t)8 * 64 * 128 * 2);
    (void)ws_size; (void)n_in; (void)out_size;

    // --- one-time prep ---
    fcvt_kernel<<<4096, 256, 0, stream>>>(
        (const float4*)features, (uint2*)fbf, (long long)N0 * 32);
    prep_wt_kernel<<<8, 256, 0, stream>>>(convW, WThi, WTlo, 128);
    fuse_fc_kernel<<<8, 256, 0, stream>>>(convW, convb, fcW, fcb, Wf, bfb);
    prep_wt_kernel<<<8, 256, 0, stream>>>(Wf, WfThi, WfTlo, 64);

    // --- bucketed CSR build (no global atomics) ---
    bcount3_kernel<<<dim3(nblkMax, 3), 256, 0, stream>>>(
        dst0, dst1, dst2, E0, E1, E2, nb0, nb1, nb2,
        nblk0, nblk1, nblk2, cO0, cO1, cO2, cnt);
    bscan_kernel<<<1, 512, 0, stream>>>(cnt, bo, rowptr3,
        nb0, nb1, nb2, nblk0, nblk1, nblk2, cO0, cO1, cO2, N1, N2, N3, r1, r2);
    bscatter3_kernel<<<dim3(nblkMax, 3), 256, 0, stream>>>(
        src0, dst0, src1, dst1, src2, dst2, E0, E1, E2, nb0, nb1, nb2,
        nblk0, nblk1, nblk2, cO0, cO1, cO2, cnt, pairs);
    bfill_kernel<<<TB, 256, 0, stream>>>(bo, pairs, elist3, rowptr3,
        nb0, nb1, nb2, N1, N2, N3, E0, E1, r1, r2);

    // --- batched type bucketing (padded bins) ---
    hipMemsetAsync(tcnt, 0, 24 * 4, stream);
    int nblkT = (totalN + 255) / 256;
    count3_kernel<<<nblkT, 256, 0, stream>>>(types1, types2, types3, N1, N2, N3, tcnt);
    scan_types3_kernel<<<1, 256, 0, stream>>>(tcnt, boff, tcur, order3, no1p, no2p);
    order3_kernel<<<nblkT, 256, 0, stream>>>(
        types1, types2, types3, N1, N2, N3, tcur, order3, no1p, no2p);

    // fold-in keys
    uint32_t fk1a, fk1b, fk2a, fk2b;
    tf2x32(0u, 42u, 0u, 1u, &fk1a, &fk1b);
    tf2x32(0u, 42u, 0u, 2u, &fk2a, &fk2b);

    // --- layer 0 ---
    aggregate_kernel<<<(N1 + 7) / 8, 256, 0, stream>>>(
        fbf, rowptr3, elist3, aggHi, aggLo, N1);
    mfma_gemm_kernel<128, true, true, true><<<(N1 + 127) / 128 + 8, 512, 0, stream>>>(
        aggHi, aggLo, order3, boff, WThi, WTlo, convb, hbf, fk1a, fk1b);

    // --- layer 1 ---
    aggregate_kernel<<<(N2 + 7) / 8, 256, 0, stream>>>(
        hbf, rowptr3 + r1, elist3 + E0, aggHi, aggLo, N2);
    mfma_gemm_kernel<128, true, true, true><<<(N2 + 127) / 128 + 8, 512, 0, stream>>>(
        aggHi, aggLo, order3 + no1p, boff + 9, WThi, WTlo, convb, hbf, fk2a, fk2b);

    // --- layer 2 (fc folded, f32 out) ---
    aggregate_kernel<<<(N3 + 7) / 8, 256, 0, stream>>>(
        hbf, rowptr3 + r2, elist3 + E0 + E1, aggHi, aggLo, N3);
    mfma_gemm_kernel<64, false, false, false><<<(N3 + 127) / 128 + 8, 512, 0, stream>>>(
        aggHi, aggLo, order3 + no2p, boff + 18, WfThi, WfTlo, bfb, d_out, 0u, 0u);
}

// Round 11
// 566.247 us; speedup vs baseline: 1.6961x; 1.2136x over previous
//
#include <hip/hip_runtime.h>
#include <cstdint>
#include <cstddef>

// ---------------------------------------------------------------------------
// JAX threefry2x32 (20 rounds). fold_in(key(42), i) = threefry((0,42),(0,i))
// partitionable 32-bit random_bits: bits = o0 ^ o1 (XOR-fold)   [validated r2]
// uniform: u = bitcast((bits>>9)|0x3f800000) - 1.0f ; keep iff u < 0.9f
// ---------------------------------------------------------------------------
__host__ __device__ inline void tf2x32(uint32_t k0, uint32_t k1,
                                       uint32_t x0, uint32_t x1,
                                       uint32_t* o0, uint32_t* o1)
{
    uint32_t ks2 = k0 ^ k1 ^ 0x1BD11BDAu;
    x0 += k0; x1 += k1;
#define TF_R(r) do { x0 += x1; x1 = (x1 << (r)) | (x1 >> (32 - (r))); x1 ^= x0; } while (0)
    TF_R(13); TF_R(15); TF_R(26); TF_R(6);
    x0 += k1;  x1 += ks2 + 1u;
    TF_R(17); TF_R(29); TF_R(16); TF_R(24);
    x0 += ks2; x1 += k0 + 2u;
    TF_R(13); TF_R(15); TF_R(26); TF_R(6);
    x0 += k0;  x1 += k1 + 3u;
    TF_R(17); TF_R(29); TF_R(16); TF_R(24);
    x0 += k1;  x1 += ks2 + 4u;
    TF_R(13); TF_R(15); TF_R(26); TF_R(6);
    x0 += ks2; x1 += k0 + 5u;
#undef TF_R
    *o0 = x0; *o1 = x1;
}

__device__ inline float drop_scale(uint32_t fk0, uint32_t fk1, uint32_t idx)
{
    uint32_t o0, o1;
    tf2x32(fk0, fk1, 0u, idx, &o0, &o1);
    uint32_t bits = o0 ^ o1;
    float u = __uint_as_float((bits >> 9) | 0x3f800000u) - 1.0f;
    return (u < 0.9f) ? (1.0f / 0.9f) : 0.0f;
}

// bf16 helpers (round-to-nearest-even)
__device__ inline ushort bf16_rn(float f)
{
    uint32_t u = __float_as_uint(f);
    u += 0x7fffu + ((u >> 16) & 1u);
    return (ushort)(u >> 16);
}
__device__ inline float bf16_f(ushort h) { return __uint_as_float(((uint32_t)h) << 16); }
__device__ inline uint32_t pack2bf(float a, float b)
{
    return (uint32_t)bf16_rn(a) | ((uint32_t)bf16_rn(b) << 16);
}
__device__ inline float bflo(uint32_t u) { return __uint_as_float(u << 16); }
__device__ inline float bfhi(uint32_t u) { return __uint_as_float(u & 0xffff0000u); }

typedef __attribute__((ext_vector_type(8))) short bf16x8;
typedef __attribute__((ext_vector_type(4))) float f32x4;

// ---------------------------------------------------------------------------
// features f32 -> packed bf16x2 (one-time per call, streaming)
// ---------------------------------------------------------------------------
__global__ __launch_bounds__(256) void fcvt_kernel(
    const float4* __restrict__ in, uint2* __restrict__ out, long long n4)
{
    long long stride = (long long)gridDim.x * 256;
    for (long long i = blockIdx.x * 256LL + threadIdx.x; i < n4; i += stride) {
        float4 v = in[i];
        out[i] = make_uint2(pack2bf(v.x, v.y), pack2bf(v.z, v.w));
    }
}

// ---------------------------------------------------------------------------
// Bucketed CSR build. Bucket = dst>>10 (1024 nodes).
// tot/bcur: global per-bucket counters (344 max) -- no cnt matrix, no scans
// over nblk columns. pairs entry: (dstLocal << 22) | src.
// ---------------------------------------------------------------------------
#define EPB 4096   // edges per block in count/scatter passes

// pass A: per-block LDS hist -> atomicAdd into global bucket totals
__global__ __launch_bounds__(256) void bcount3_kernel(
    const int* __restrict__ d0, const int* __restrict__ d1, const int* __restrict__ d2,
    int E0, int E1, int E2, int nb0, int nb1, int nb2,
    int nblk0, int nblk1, int nblk2, uint32_t* __restrict__ tot)
{
    int L = blockIdx.y;
    const int* dst = L == 0 ? d0 : (L == 1 ? d1 : d2);
    int E  = L == 0 ? E0 : (L == 1 ? E1 : E2);
    int NB = L == 0 ? nb0 : (L == 1 ? nb1 : nb2);
    int nblk = L == 0 ? nblk0 : (L == 1 ? nblk1 : nblk2);
    int gO = L == 0 ? 0 : (L == 1 ? nb0 : nb0 + nb1);
    if ((int)blockIdx.x >= nblk) return;

    __shared__ uint32_t lh[256];
    int tid = threadIdx.x;
    lh[tid] = 0;
    __syncthreads();
    int base = blockIdx.x * EPB;
    for (int i = tid; i < EPB; i += 256) {
        int e = base + i;
        if (e < E) atomicAdd(&lh[((uint32_t)dst[e]) >> 10], 1u);
    }
    __syncthreads();
    if (tid < NB && lh[tid]) atomicAdd(&tot[gO + tid], lh[tid]);
}

// pass S: tiny 1-block scan of bucket totals -> bo[], rowptr sentinels, bcur
__global__ __launch_bounds__(512) void bscan_small_kernel(
    const uint32_t* __restrict__ tot, uint32_t* __restrict__ bo,
    uint32_t* __restrict__ bcur, uint32_t* __restrict__ rowptr3,
    int nb0, int nb1, int nb2, int N1, int N2, int N3, int r1, int r2)
{
    __shared__ uint32_t bol[348];
    int t = threadIdx.x;
    int TB = nb0 + nb1 + nb2;
    if (t < 3) {
        int nb = t == 0 ? nb0 : (t == 1 ? nb1 : nb2);
        int g0 = t == 0 ? 0 : (t == 1 ? nb0 : nb0 + nb1);
        int gi0 = g0 + t;
        uint32_t run = 0;
        for (int i = 0; i < nb; ++i) { bol[gi0 + i] = run; run += tot[g0 + i]; }
        bol[gi0 + nb] = run;
        int rp = t == 0 ? 0 : (t == 1 ? r1 : r2);
        int N = t == 0 ? N1 : (t == 1 ? N2 : N3);
        rowptr3[rp + N] = run;
    }
    __syncthreads();
    for (int i = t; i < TB + 3; i += 512) bo[i] = bol[i];
    if (t < TB) {
        int layer = t < nb0 ? 0 : (t < nb0 + nb1 ? 1 : 2);
        bcur[t] = bol[t + layer];
    }
}

// pass B: 2-pass scatter: LDS hist -> one global atomicAdd per (block,bucket)
// to reserve a contiguous run -> LDS-rank write. Buckets stay contiguous.
__global__ __launch_bounds__(256) void bscatter3_kernel(
    const int* __restrict__ s0, const int* __restrict__ d0,
    const int* __restrict__ s1, const int* __restrict__ d1,
    const int* __restrict__ s2, const int* __restrict__ d2,
    int E0, int E1, int E2, int nb0, int nb1, int nb2,
    int nblk0, int nblk1, int nblk2,
    uint32_t* __restrict__ bcur, uint32_t* __restrict__ pairs)
{
    int L = blockIdx.y;
    const int* src = L == 0 ? s0 : (L == 1 ? s1 : s2);
    const int* dst = L == 0 ? d0 : (L == 1 ? d1 : d2);
    int E  = L == 0 ? E0 : (L == 1 ? E1 : E2);
    int NB = L == 0 ? nb0 : (L == 1 ? nb1 : nb2);
    int nblk = L == 0 ? nblk0 : (L == 1 ? nblk1 : nblk2);
    int gO = L == 0 ? 0 : (L == 1 ? nb0 : nb0 + nb1);
    uint32_t* pr = pairs + (L == 0 ? 0 : (L == 1 ? E0 : E0 + E1));
    if ((int)blockIdx.x >= nblk) return;

    __shared__ uint32_t lh[256], lbase[256], rank[256];
    int tid = threadIdx.x;
    lh[tid] = 0; rank[tid] = 0;
    __syncthreads();
    int base = blockIdx.x * EPB;
    for (int i = tid; i < EPB; i += 256) {
        int e = base + i;
        if (e < E) atomicAdd(&lh[((uint32_t)dst[e]) >> 10], 1u);
    }
    __syncthreads();
    if (tid < NB && lh[tid]) lbase[tid] = atomicAdd(&bcur[gO + tid], lh[tid]);
    __syncthreads();
    for (int i = tid; i < EPB; i += 256) {
        int e = base + i;
        if (e < E) {
            uint32_t d = (uint32_t)dst[e];
            uint32_t bk = d >> 10;
            uint32_t r = atomicAdd(&rank[bk], 1u);
            pr[lbase[bk] + r] = ((d & 1023u) << 22) | (uint32_t)src[e];
        }
    }
}

// pass C: one block per bucket: LDS hist -> scan -> rowptr + fine elist fill
__global__ __launch_bounds__(256) void bfill_kernel(
    const uint32_t* __restrict__ bo, const uint32_t* __restrict__ pairs,
    int* __restrict__ elist3, uint32_t* __restrict__ rowptr3,
    int nb0, int nb1, int nb2, int N1, int N2, int N3,
    int E0, int E1, int r1, int r2)
{
    __shared__ uint32_t hist[1024];
    __shared__ uint32_t cur[1024];
    __shared__ uint32_t psum[256];
    int g = blockIdx.x, tid = threadIdx.x;
    int layer, lb, N, Eoff, rp;
    if (g < nb0) { layer = 0; lb = g; N = N1; Eoff = 0; rp = 0; }
    else if (g < nb0 + nb1) { layer = 1; lb = g - nb0; N = N2; Eoff = E0; rp = r1; }
    else { layer = 2; lb = g - nb0 - nb1; N = N3; Eoff = E0 + E1; rp = r2; }
    uint32_t off = bo[g + layer], end = bo[g + layer + 1];
    int nodeBase = lb << 10;
    int nodesIn = N - nodeBase; if (nodesIn > 1024) nodesIn = 1024;

    #pragma unroll
    for (int i = 0; i < 4; ++i) hist[tid * 4 + i] = 0;
    __syncthreads();
    for (uint32_t e = off + tid; e < end; e += 256)
        atomicAdd(&hist[pairs[Eoff + e] >> 22], 1u);
    __syncthreads();

    uint32_t x[4]; uint32_t s = 0;
    #pragma unroll
    for (int i = 0; i < 4; ++i) { x[i] = hist[tid * 4 + i]; s += x[i]; }
    psum[tid] = s; __syncthreads();
    uint32_t inc = s;
    #pragma unroll
    for (int o = 1; o < 256; o <<= 1) {
        uint32_t y = (tid >= o) ? psum[tid - o] : 0u;
        __syncthreads();
        inc += y; psum[tid] = inc;
        __syncthreads();
    }
    uint32_t run = off + inc - s;
    #pragma unroll
    for (int i = 0; i < 4; ++i) { cur[tid * 4 + i] = run; run += x[i]; }
    __syncthreads();

    for (int i = tid; i < nodesIn; i += 256)
        rowptr3[rp + nodeBase + i] = cur[i];
    __syncthreads();

    for (uint32_t e = off + tid; e < end; e += 256) {
        uint32_t pk = pairs[Eoff + e];
        uint32_t pos = atomicAdd(&cur[pk >> 22], 1u);
        elist3[Eoff + pos] = (int)(pk & 0x3FFFFFu);
    }
}

// ---------------------------------------------------------------------------
// Batched type bucketing; order3 PADDED to 128-multiples per bin (pad = -1)
// ---------------------------------------------------------------------------
__global__ __launch_bounds__(256) void count3_kernel(
    const int* __restrict__ t0, const int* __restrict__ t1, const int* __restrict__ t2,
    int n0, int n1, int n2, uint32_t* __restrict__ tcnt)
{
    __shared__ uint32_t lh[24];
    int tid = threadIdx.x;
    if (tid < 24) lh[tid] = 0;
    __syncthreads();
    int i = blockIdx.x * 256 + tid;
    if (i < n0) atomicAdd(&lh[t0[i]], 1u);
    else if (i < n0 + n1) atomicAdd(&lh[8 + t1[i - n0]], 1u);
    else if (i < n0 + n1 + n2) atomicAdd(&lh[16 + t2[i - n0 - n1]], 1u);
    __syncthreads();
    if (tid < 24 && lh[tid]) atomicAdd(&tcnt[tid], lh[tid]);
}

__global__ __launch_bounds__(256) void scan_types3_kernel(
    const uint32_t* __restrict__ tcnt, int* __restrict__ boff,
    uint32_t* __restrict__ tcur, int* __restrict__ order3, int no1p, int no2p)
{
    __shared__ int pB[27];
    __shared__ int cnts[24];
    int tid = threadIdx.x;
    if (tid == 0) {
        for (int L = 0; L < 3; ++L) {
            int a = 0;
            for (int t = 0; t < 8; ++t) {
                pB[L * 9 + t] = a;
                int c = (int)tcnt[L * 8 + t];
                cnts[L * 8 + t] = c;
                tcur[L * 8 + t] = (uint32_t)a;
                a += (c + 127) & ~127;
            }
            pB[L * 9 + 8] = a;
        }
    }
    __syncthreads();
    if (tid < 27) boff[tid] = pB[tid];
    if (tid < 24) {
        int L = tid >> 3, t = tid & 7;
        int noff = L == 0 ? 0 : (L == 1 ? no1p : no2p);
        int s = pB[L * 9 + t] + cnts[tid];
        int e2 = pB[L * 9 + t + 1];
        for (int k = s; k < e2; ++k) order3[noff + k] = -1;
    }
}

__global__ __launch_bounds__(256) void order3_kernel(
    const int* __restrict__ t0, const int* __restrict__ t1, const int* __restrict__ t2,
    int n0, int n1, int n2, uint32_t* __restrict__ tcur,
    int* __restrict__ order3, int no1p, int no2p)
{
    __shared__ uint32_t lh[24], lbase[24];
    int tid = threadIdx.x;
    if (tid < 24) lh[tid] = 0;
    __syncthreads();
    int i = blockIdx.x * 256 + tid;
    int slot = -1, idx = 0; uint32_t r = 0;
    if (i < n0) { idx = i; slot = t0[idx]; }
    else if (i < n0 + n1) { idx = i - n0; slot = 8 + t1[idx]; }
    else if (i < n0 + n1 + n2) { idx = i - n0 - n1; slot = 16 + t2[idx]; }
    if (slot >= 0) r = atomicAdd(&lh[slot], 1u);
    __syncthreads();
    if (tid < 24 && lh[tid]) lbase[tid] = atomicAdd(&tcur[tid], lh[tid]);
    __syncthreads();
    if (slot >= 0) {
        int noff = slot < 8 ? 0 : (slot < 16 ? no1p : no2p);
        order3[noff + lbase[slot] + r] = idx;
    }
}

// ---------------------------------------------------------------------------
// Gather-aggregate: 2 nodes per wave, fused 8+8-unrolled main loop -> 16
// outstanding gathers. f32 accumulate; bf16 hi/lo out.
// ---------------------------------------------------------------------------
__global__ __launch_bounds__(256) void aggregate_kernel(
    const uint32_t* __restrict__ hbf, const uint32_t* __restrict__ rowptr,
    const int* __restrict__ elist, uint32_t* __restrict__ agghi,
    uint32_t* __restrict__ agglo, int nout)
{
    int wid = threadIdx.x >> 6, lane = threadIdx.x & 63;
    int n0 = blockIdx.x * 8 + wid * 2;
    if (n0 >= nout) return;
    int n1 = n0 + 1;
    bool v1 = (n1 < nout);
    uint32_t b0 = rowptr[n0], e0 = rowptr[n0 + 1];
    uint32_t b1 = v1 ? rowptr[n1] : 0u, e1 = v1 ? rowptr[n1 + 1] : 0u;
    const uint32_t* base = hbf + lane;
    float a0x = 0.f, a0y = 0.f, a1x = 0.f, a1y = 0.f;
    uint32_t i0 = b0, i1 = b1;

    while (i0 + 8 <= e0 && i1 + 8 <= e1) {
        uint32_t u[8], w[8];
        #pragma unroll
        for (int k = 0; k < 8; ++k) u[k] = base[(size_t)elist[i0 + k] * 64];
        #pragma unroll
        for (int k = 0; k < 8; ++k) w[k] = base[(size_t)elist[i1 + k] * 64];
        #pragma unroll
        for (int k = 0; k < 8; ++k) { a0x += bflo(u[k]); a0y += bfhi(u[k]); }
        #pragma unroll
        for (int k = 0; k < 8; ++k) { a1x += bflo(w[k]); a1y += bfhi(w[k]); }
        i0 += 8; i1 += 8;
    }
    while (i0 + 4 <= e0 && i1 + 4 <= e1) {
        uint32_t u[4], w[4];
        #pragma unroll
        for (int k = 0; k < 4; ++k) u[k] = base[(size_t)elist[i0 + k] * 64];
        #pragma unroll
        for (int k = 0; k < 4; ++k) w[k] = base[(size_t)elist[i1 + k] * 64];
        #pragma unroll
        for (int k = 0; k < 4; ++k) { a0x += bflo(u[k]); a0y += bfhi(u[k]); }
        #pragma unroll
        for (int k = 0; k < 4; ++k) { a1x += bflo(w[k]); a1y += bfhi(w[k]); }
        i0 += 4; i1 += 4;
    }
    while (i0 + 4 <= e0) {
        uint32_t u[4];
        #pragma unroll
        for (int k = 0; k < 4; ++k) u[k] = base[(size_t)elist[i0 + k] * 64];
        #pragma unroll
        for (int k = 0; k < 4; ++k) { a0x += bflo(u[k]); a0y += bfhi(u[k]); }
        i0 += 4;
    }
    while (i1 + 4 <= e1) {
        uint32_t w[4];
        #pragma unroll
        for (int k = 0; k < 4; ++k) w[k] = base[(size_t)elist[i1 + k] * 64];
        #pragma unroll
        for (int k = 0; k < 4; ++k) { a1x += bflo(w[k]); a1y += bfhi(w[k]); }
        i1 += 4;
    }
    for (; i0 < e0; ++i0) {
        uint32_t u = base[(size_t)elist[i0] * 64];
        a0x += bflo(u); a0y += bfhi(u);
    }
    for (; i1 < e1; ++i1) {
        uint32_t w = base[(size_t)elist[i1] * 64];
        a1x += bflo(w); a1y += bfhi(w);
    }

    float sc0 = 1.0f / fmaxf((float)(e0 - b0), 1.0f);
    a0x *= sc0; a0y *= sc0;
    ushort hx = bf16_rn(a0x); ushort lx = bf16_rn(a0x - bf16_f(hx));
    ushort hy = bf16_rn(a0y); ushort ly = bf16_rn(a0y - bf16_f(hy));
    agghi[(size_t)n0 * 64 + lane] = (uint32_t)hx | ((uint32_t)hy << 16);
    agglo[(size_t)n0 * 64 + lane] = (uint32_t)lx | ((uint32_t)ly << 16);
    if (v1) {
        float sc1 = 1.0f / fmaxf((float)(e1 - b1), 1.0f);
        a1x *= sc1; a1y *= sc1;
        ushort hx1 = bf16_rn(a1x); ushort lx1 = bf16_rn(a1x - bf16_f(hx1));
        ushort hy1 = bf16_rn(a1y); ushort ly1 = bf16_rn(a1y - bf16_f(hy1));
        agghi[(size_t)n1 * 64 + lane] = (uint32_t)hx1 | ((uint32_t)hy1 << 16);
        agglo[(size_t)n1 * 64 + lane] = (uint32_t)lx1 | ((uint32_t)ly1 << 16);
    }
}

// ---------------------------------------------------------------------------
// Weight prep: src f32 [8][128][C] (k-major) -> dst bf16 hi/lo [8][C][128]
// transposed + XOR-swizzled: chunk' = (k>>3) ^ (c&15).
// ---------------------------------------------------------------------------
__global__ __launch_bounds__(256) void prep_wt_kernel(
    const float* __restrict__ src8, ushort* __restrict__ dsthi,
    ushort* __restrict__ dstlo, int C)
{
    int t = blockIdx.x;
    const float* S = src8 + (size_t)t * 128 * C;
    ushort* DH = dsthi + (size_t)t * C * 128;
    ushort* DL = dstlo + (size_t)t * C * 128;
    for (int idx = threadIdx.x; idx < 128 * C; idx += 256) {
        int k = idx / C, c = idx % C;
        float v = S[(size_t)k * C + c];
        ushort hi = bf16_rn(v);
        ushort lo = bf16_rn(v - bf16_f(hi));
        int pos = c * 128 + ((((k >> 3) ^ (c & 15)) << 3) | (k & 7));
        DH[pos] = hi; DL[pos] = lo;
    }
}

// ---------------------------------------------------------------------------
// MFMA GEMM (split-bf16): out[n] = [relu](agg[n] @ W[t] + b[t]) [* dropout]
// A fragments loaded DIRECTLY from global (no cross-lane reuse -> no LDS);
// only W (+ND) staged in LDS: 64.5KB @DOUT=128 -> 2 blocks/CU, 4 waves/SIMD.
// ---------------------------------------------------------------------------
template<int DOUT, bool RELU, bool DROP, bool OUTBF>
__global__ __launch_bounds__(512) void mfma_gemm_kernel(
    const uint32_t* __restrict__ agghi, const uint32_t* __restrict__ agglo,
    const int* __restrict__ order, const int* __restrict__ off,
    const ushort* __restrict__ WThi, const ushort* __restrict__ WTlo,
    const float* __restrict__ bias8, void* __restrict__ houtv,
    uint32_t fk0, uint32_t fk1)
{
    __shared__ ushort WH[DOUT * 128];
    __shared__ ushort WL[DOUT * 128];
    __shared__ int ND[128];

    int b0 = blockIdx.x * 128;
    if (b0 >= off[8]) return;
    int t = 0;
    #pragma unroll
    for (int u = 1; u < 8; ++u) if (b0 >= off[u]) ++t;
    int tid = threadIdx.x;

    if (tid < 128) ND[tid] = order[b0 + tid];

    // stage W (pre-transposed, pre-swizzled -> straight copy)
    {
        const float4* sh = (const float4*)(WThi + (size_t)t * DOUT * 128);
        const float4* sl = (const float4*)(WTlo + (size_t)t * DOUT * 128);
        float4* dh = (float4*)WH; float4* dl = (float4*)WL;
        #pragma unroll
        for (int it = 0; it < DOUT * 16 / 512; ++it) {
            int c = it * 512 + tid;
            dh[c] = sh[c]; dl[c] = sl[c];
        }
    }
    __syncthreads();

    int wid = tid >> 6, lane = tid & 63;
    int r15 = lane & 15, q = lane >> 4;
    int arow = wid * 16 + r15;
    int nd_a = ND[arow];

    // A fragments straight from global (agg is L3-resident)
    const bf16x8* gh = (const bf16x8*)agghi;
    const bf16x8* gl = (const bf16x8*)agglo;
    bf16x8 zero8 = (bf16x8){0, 0, 0, 0, 0, 0, 0, 0};
    bf16x8 ahv[4], alv[4];
    {
        size_t rowb = (size_t)(nd_a < 0 ? 0 : nd_a) * 16;
        #pragma unroll
        for (int ks = 0; ks < 4; ++ks) {
            size_t ix = rowb + (q + ks * 4);
            ahv[ks] = (nd_a >= 0) ? gh[ix] : zero8;
            alv[ks] = (nd_a >= 0) ? gl[ix] : zero8;
        }
    }

    constexpr int NF = DOUT / 16;
    f32x4 acc[NF];
    #pragma unroll
    for (int i = 0; i < NF; ++i) acc[i] = (f32x4){0.f, 0.f, 0.f, 0.f};

    const bf16x8* WHp = (const bf16x8*)WH;
    const bf16x8* WLp = (const bf16x8*)WL;

    #pragma unroll
    for (int ks = 0; ks < 4; ++ks) {
        int sch = (q + ks * 4) ^ r15;
        bf16x8 ah = ahv[ks];
        bf16x8 al = alv[ks];
        #pragma unroll
        for (int nf = 0; nf < NF; ++nf) {
            int col = nf * 16 + r15;
            bf16x8 bh = WHp[col * 16 + sch];
            bf16x8 bl = WLp[col * 16 + sch];
            acc[nf] = __builtin_amdgcn_mfma_f32_16x16x32_bf16(ah, bh, acc[nf], 0, 0, 0);
            acc[nf] = __builtin_amdgcn_mfma_f32_16x16x32_bf16(ah, bl, acc[nf], 0, 0, 0);
            acc[nf] = __builtin_amdgcn_mfma_f32_16x16x32_bf16(al, bh, acc[nf], 0, 0, 0);
        }
    }

    // epilogue: C/D row = wid*16 + q*4 + r, col = nf*16 + r15
    int ndr[4];
    #pragma unroll
    for (int r = 0; r < 4; ++r) ndr[r] = ND[wid * 16 + q * 4 + r];
    const float* bptr = bias8 + (size_t)t * DOUT;

    #pragma unroll
    for (int nf = 0; nf < NF; ++nf) {
        int col = nf * 16 + r15;
        float bv = bptr[col];
        float vr[4];
        #pragma unroll
        for (int r = 0; r < 4; ++r) {
            float v = acc[nf][r] + bv;
            if (RELU) v = fmaxf(v, 0.f);
            if (DROP) {
                int nd = ndr[r] < 0 ? 0 : ndr[r];
                v *= drop_scale(fk0, fk1, (uint32_t)nd * 128u + (uint32_t)col);
            }
            vr[r] = v;
        }
        if (OUTBF) {
            uint32_t* hb = (uint32_t*)houtv;
            #pragma unroll
            for (int r = 0; r < 4; ++r) {
                float w = __shfl_xor(vr[r], 1, 64);
                if ((lane & 1) == 0 && ndr[r] >= 0)
                    hb[(size_t)ndr[r] * (DOUT / 2) + (col >> 1)] = pack2bf(vr[r], w);
            }
        } else {
            float* ho = (float*)houtv;
            #pragma unroll
            for (int r = 0; r < 4; ++r)
                if (ndr[r] >= 0) ho[(size_t)ndr[r] * DOUT + col] = vr[r];
        }
    }
}

// ---------------------------------------------------------------------------
// fc fusion: Wf[t] = W[t] @ fcW (128x64 f32), bf[t] = b[t] @ fcW + fcb
// ---------------------------------------------------------------------------
__global__ __launch_bounds__(256) void fuse_fc_kernel(
    const float* __restrict__ convW, const float* __restrict__ convb,
    const float* __restrict__ fcW, const float* __restrict__ fcb,
    float* __restrict__ Wf, float* __restrict__ bf)
{
    __shared__ float F[128 * 64];
    int t = blockIdx.x, tid = threadIdx.x;
    #pragma unroll
    for (int it = 0; it < 8; ++it) {
        int idx4 = (it * 256 + tid) * 4;
        *(float4*)&F[idx4] = *(const float4*)&fcW[idx4];
    }
    __syncthreads();

    int r = tid >> 1, cb = (tid & 1) * 32;
    const float* Wrow = convW + (size_t)t * 16384 + (size_t)r * 128;
    float acc[32];
    #pragma unroll
    for (int c = 0; c < 32; ++c) acc[c] = 0.f;
    for (int k = 0; k < 128; ++k) {
        float w = Wrow[k];
        #pragma unroll
        for (int c = 0; c < 32; ++c) acc[c] += w * F[k * 64 + cb + c];
    }
    float* outp = Wf + (size_t)t * 8192 + (size_t)r * 64 + cb;
    #pragma unroll
    for (int c = 0; c < 32; ++c) outp[c] = acc[c];

    if (tid < 64) {
        float a = fcb[tid];
        const float* bt = convb + (size_t)t * 128;
        for (int k = 0; k < 128; ++k) a += bt[k] * F[k * 64 + tid];
        bf[(size_t)t * 64 + tid] = a;
    }
}

// ---------------------------------------------------------------------------
extern "C" void kernel_launch(void* const* d_in, const int* in_sizes, int n_in,
                              void* d_out, int out_size, void* d_ws, size_t ws_size,
                              hipStream_t stream)
{
    const float* features = (const float*)d_in[0];
    const int*   src0 = (const int*)d_in[1];
    const int*   dst0 = (const int*)d_in[2];
    const int*   types1 = (const int*)d_in[3];
    const int*   src1 = (const int*)d_in[4];
    const int*   dst1 = (const int*)d_in[5];
    const int*   types2 = (const int*)d_in[6];
    const int*   src2 = (const int*)d_in[7];
    const int*   dst2 = (const int*)d_in[8];
    const int*   types3 = (const int*)d_in[9];
    const float* convW = (const float*)d_in[10];
    const float* convb = (const float*)d_in[11];
    const float* fcW   = (const float*)d_in[12];
    const float* fcb   = (const float*)d_in[13];

    int N0 = in_sizes[0] / 128;
    int E0 = in_sizes[1], N1 = in_sizes[3];
    int E1 = in_sizes[4], N2 = in_sizes[6];
    int E2 = in_sizes[7], N3 = in_sizes[9];
    int totalN = N1 + N2 + N3;
    int totalE = E0 + E1 + E2;
    int r1 = N1 + 1, r2 = N1 + 1 + N2 + 1;           // rowptr offsets
    int no1p = N1 + 1024, no2p = no1p + N2 + 1024;   // padded order3 offsets
    int maxN = N1 > N2 ? N1 : N2; if (N3 > maxN) maxN = N3;

    // bucket-sort geometry
    int nb0 = (N1 + 1023) >> 10, nb1 = (N2 + 1023) >> 10, nb2 = (N3 + 1023) >> 10;
    int TB = nb0 + nb1 + nb2;
    int nblk0 = (E0 + EPB - 1) / EPB, nblk1 = (E1 + EPB - 1) / EPB, nblk2 = (E2 + EPB - 1) / EPB;
    int nblkMax = nblk0 > nblk1 ? nblk0 : nblk1; if (nblk2 > nblkMax) nblkMax = nblk2;

    char* ws = (char*)d_ws;
    size_t woff = 0;
    auto alloc = [&](size_t bytes) -> void* {
        void* p = ws + woff;
        woff = (woff + bytes + 255) & ~(size_t)255;
        return p;
    };
    uint32_t* fbf     = (uint32_t*)alloc((size_t)N0 * 64 * 4);    // packed bf16 features
    uint32_t* hbf     = fbf;                                      // alias: h after L0 agg
    uint32_t* aggHi   = (uint32_t*)alloc((size_t)maxN * 64 * 4);
    uint32_t* pairs   = aggHi;                                    // alias: dead before agg
    uint32_t* aggLo   = (uint32_t*)alloc((size_t)maxN * 64 * 4);
    uint32_t* rowptr3 = (uint32_t*)alloc((size_t)(totalN + 3) * 4);
    int*      elist3  = (int*)alloc((size_t)totalE * 4);
    int*      order3  = (int*)alloc((size_t)(totalN + 3 * 1024) * 4);
    uint32_t* tot     = (uint32_t*)alloc((size_t)(TB + 8) * 4);
    uint32_t* bcur    = (uint32_t*)alloc((size_t)(TB + 8) * 4);
    uint32_t* bo      = (uint32_t*)alloc((size_t)(TB + 3) * 4);
    uint32_t* tcnt    = (uint32_t*)alloc(24 * 4);
    int*      boff    = (int*)alloc(27 * 4);
    uint32_t* tcur    = (uint32_t*)alloc(24 * 4);
    float*    Wf      = (float*)alloc((size_t)8 * 128 * 64 * 4);
    float*    bfb     = (float*)alloc((size_t)8 * 64 * 4);
    ushort*   WThi    = (ushort*)alloc((size_t)8 * 128 * 128 * 2);
    ushort*   WTlo    = (ushort*)alloc((size_t)8 * 128 * 128 * 2);
    ushort*   WfThi   = (ushort*)alloc((size_t)8 * 64 * 128 * 2);
    ushort*   WfTlo   = (ushort*)alloc((size_t)8 * 64 * 128 * 2);
    (void)ws_size; (void)n_in; (void)out_size;

    // --- one-time prep ---
    fcvt_kernel<<<4096, 256, 0, stream>>>(
        (const float4*)features, (uint2*)fbf, (long long)N0 * 32);
    prep_wt_kernel<<<8, 256, 0, stream>>>(convW, WThi, WTlo, 128);
    fuse_fc_kernel<<<8, 256, 0, stream>>>(convW, convb, fcW, fcb, Wf, bfb);
    prep_wt_kernel<<<8, 256, 0, stream>>>(Wf, WfThi, WfTlo, 64);

    // --- bucketed CSR build (global per-bucket counters; no column scans) ---
    hipMemsetAsync(tot, 0, (size_t)TB * 4, stream);
    bcount3_kernel<<<dim3(nblkMax, 3), 256, 0, stream>>>(
        dst0, dst1, dst2, E0, E1, E2, nb0, nb1, nb2,
        nblk0, nblk1, nblk2, tot);
    bscan_small_kernel<<<1, 512, 0, stream>>>(tot, bo, bcur, rowptr3,
        nb0, nb1, nb2, N1, N2, N3, r1, r2);
    bscatter3_kernel<<<dim3(nblkMax, 3), 256, 0, stream>>>(
        src0, dst0, src1, dst1, src2, dst2, E0, E1, E2, nb0, nb1, nb2,
        nblk0, nblk1, nblk2, bcur, pairs);
    bfill_kernel<<<TB, 256, 0, stream>>>(bo, pairs, elist3, rowptr3,
        nb0, nb1, nb2, N1, N2, N3, E0, E1, r1, r2);

    // --- batched type bucketing (padded bins) ---
    hipMemsetAsync(tcnt, 0, 24 * 4, stream);
    int nblkT = (totalN + 255) / 256;
    count3_kernel<<<nblkT, 256, 0, stream>>>(types1, types2, types3, N1, N2, N3, tcnt);
    scan_types3_kernel<<<1, 256, 0, stream>>>(tcnt, boff, tcur, order3, no1p, no2p);
    order3_kernel<<<nblkT, 256, 0, stream>>>(
        types1, types2, types3, N1, N2, N3, tcur, order3, no1p, no2p);

    // fold-in keys
    uint32_t fk1a, fk1b, fk2a, fk2b;
    tf2x32(0u, 42u, 0u, 1u, &fk1a, &fk1b);
    tf2x32(0u, 42u, 0u, 2u, &fk2a, &fk2b);

    // --- layer 0 ---
    aggregate_kernel<<<(N1 + 7) / 8, 256, 0, stream>>>(
        fbf, rowptr3, elist3, aggHi, aggLo, N1);
    mfma_gemm_kernel<128, true, true, true><<<(N1 + 127) / 128 + 8, 512, 0, stream>>>(
        aggHi, aggLo, order3, boff, WThi, WTlo, convb, hbf, fk1a, fk1b);

    // --- layer 1 ---
    aggregate_kernel<<<(N2 + 7) / 8, 256, 0, stream>>>(
        hbf, rowptr3 + r1, elist3 + E0, aggHi, aggLo, N2);
    mfma_gemm_kernel<128, true, true, true><<<(N2 + 127) / 128 + 8, 512, 0, stream>>>(
        aggHi, aggLo, order3 + no1p, boff + 9, WThi, WTlo, convb, hbf, fk2a, fk2b);

    // --- layer 2 (fc folded, f32 out) ---
    aggregate_kernel<<<(N3 + 7) / 8, 256, 0, stream>>>(
        hbf, rowptr3 + r2, elist3 + E0 + E1, aggHi, aggLo, N3);
    mfma_gemm_kernel<64, false, false, false><<<(N3 + 127) / 128 + 8, 512, 0, stream>>>(
        aggHi, aggLo, order3 + no2p, boff + 18, WfThi, WfTlo, bfb, d_out, 0u, 0u);
}